// Round 6
// baseline (7025.401 us; speedup 1.0000x reference)
//
#include <hip/hip_runtime.h>
#include <hip/hip_bf16.h>
#include <cstdint>

#define T_STEPS 100
#define BATCH 256
#define NIN 700
#define H1 2048
#define H2 2048
#define NOUT 20
#define VKS 8           // K-split factor for per-step V GEMM (grid 32nt x 8ks)
#define TCHUNK 10       // timesteps per hoisted-GEMM chunk (10 chunks)

typedef __attribute__((ext_vector_type(8))) short bf16x8;
typedef __attribute__((ext_vector_type(4))) float f32x4;
typedef unsigned long long ull;

__device__ __forceinline__ void async16(void* lds, const void* g) {
    __builtin_amdgcn_global_load_lds(
        (const __attribute__((address_space(1))) unsigned int*)g,
        (__attribute__((address_space(3))) unsigned int*)lds, 16, 0, 0);
}

__device__ __forceinline__ unsigned short f2bf(float x) {
    __hip_bfloat16 h = __float2bfloat16(x);
    return *(unsigned short*)&h;
}
__device__ __forceinline__ float bf2f(unsigned short u) {
    __hip_bfloat16 h = *(__hip_bfloat16*)&u;
    return __bfloat162float(h);
}

// ---------------- split W2|V into bf16 hi/mid/lo, layout [term][j][4096k] ----
// k<2048 = W2 row, k>=2048 = V row.
__global__ __launch_bounds__(256) void split_kernel(
    const float* __restrict__ W2, const float* __restrict__ V,
    unsigned short* __restrict__ Bsplit)
{
    const size_t D = (size_t)2048 * 4096;
    size_t i = (size_t)blockIdx.x * 256 + threadIdx.x;
    int j = (int)(i >> 12), k = (int)(i & 4095);
    float w = (k < 2048) ? W2[(size_t)j * 2048 + k] : V[(size_t)j * 2048 + (k - 2048)];
    unsigned short h = f2bf(w);
    float r1 = w - bf2f(h);
    unsigned short m = f2bf(r1);
    float r2 = r1 - bf2f(m);
    unsigned short l = f2bf(r2);
    Bsplit[i] = h;
    Bsplit[D + i] = m;
    Bsplit[2 * D + i] = l;
}

// ---------------- split W1 into granule-major bf16 planes ------------------
// W1f[term][g 0..87][j 0..2047][8] ; k = g*8+e, zero-padded k>=700.
__global__ __launch_bounds__(256) void w1split_kernel(
    const float* __restrict__ W1, unsigned short* __restrict__ W1f)
{
    const size_t P = (size_t)88 * 2048 * 8;   // elems per term
    int id = blockIdx.x * 256 + threadIdx.x;  // 0..180223
    int g = id >> 11, j = id & 2047;
    unsigned short h8[8], m8[8], l8[8];
    #pragma unroll
    for (int e = 0; e < 8; ++e) {
        int k = g * 8 + e;
        float v = (k < NIN) ? W1[(size_t)j * NIN + k] : 0.f;
        unsigned short h = f2bf(v); float r1 = v - bf2f(h);
        unsigned short m = f2bf(r1); float r2 = r1 - bf2f(m);
        h8[e] = h; m8[e] = m; l8[e] = f2bf(r2);
    }
    size_t base = (((size_t)g * 2048) + j) * 8;
    *(uint4*)(W1f + base)         = *(uint4*)h8;
    *(uint4*)(W1f + P + base)     = *(uint4*)m8;
    *(uint4*)(W1f + 2 * P + base) = *(uint4*)l8;
}

// ---------------- layer 1 via MFMA: x@W1.T (6-term bf16) + scan + bitpack ----
// grid 2048 = 8 jt (bid&7, XCD-locality) x 256 b. Block 256 thr / 4 waves.
__global__ __launch_bounds__(256) void l1m_kernel(
    const float* __restrict__ data, const unsigned short* __restrict__ W1f,
    const float* __restrict__ b1,
    const float* __restrict__ p_beta1, const float* __restrict__ p_thr1,
    ull* __restrict__ s1bits)
{
    __shared__ __align__(16) char smem[33280];  // union: Af 21.5KB | Cw 4x8.3KB
    unsigned short* Af = (unsigned short*)smem; // [3 term][4 g][112 t][8]
    const int tid = threadIdx.x, lane = tid & 63, w = tid >> 6;
    const int n16 = lane & 15, q = lane >> 4;
    const int jt = blockIdx.x & 7, b = blockIdx.x >> 3;
    const int j0w = jt * 256 + w * 64;
    const float* xb = data + (size_t)b * (NIN * T_STEPS);
    const size_t P = (size_t)88 * 2048 * 8;

    f32x4 acc[7][4] = {};
    for (int c = 0; c < 22; ++c) {
        const int kbase = c * 32;
        for (int it = tid; it < 448; it += 256) {
            int g = it / 112, t = it - g * 112;
            unsigned short h8[8], m8[8], l8[8];
            #pragma unroll
            for (int e = 0; e < 8; ++e) {
                int k = kbase + g * 8 + e;
                float v = (t < T_STEPS && k < NIN) ? xb[(size_t)k * T_STEPS + t] : 0.f;
                unsigned short h = f2bf(v); float r1 = v - bf2f(h);
                unsigned short m = f2bf(r1); float r2 = r1 - bf2f(m);
                h8[e] = h; m8[e] = m; l8[e] = f2bf(r2);
            }
            unsigned short* dst = Af + g * 896 + t * 8;
            *(uint4*)(dst)        = *(uint4*)h8;
            *(uint4*)(dst + 3584) = *(uint4*)m8;
            *(uint4*)(dst + 7168) = *(uint4*)l8;
        }
        __syncthreads();
        bf16x8 bh[4], bm[4], bl[4];
        const size_t gq = (size_t)(c * 4 + q);
        #pragma unroll
        for (int n = 0; n < 4; ++n) {
            size_t off = (gq * 2048 + (size_t)(j0w + n * 16 + n16)) * 8;
            bh[n] = *(const bf16x8*)(W1f + off);
            bm[n] = *(const bf16x8*)(W1f + P + off);
            bl[n] = *(const bf16x8*)(W1f + 2 * P + off);
        }
        #pragma unroll
        for (int m = 0; m < 7; ++m) {
            const unsigned short* ap = Af + q * 896 + (m * 16 + n16) * 8;
            bf16x8 ah = *(const bf16x8*)(ap);
            bf16x8 am = *(const bf16x8*)(ap + 3584);
            bf16x8 al = *(const bf16x8*)(ap + 7168);
            #pragma unroll
            for (int n = 0; n < 4; ++n) {
                acc[m][n] = __builtin_amdgcn_mfma_f32_16x16x32_bf16(ah, bh[n], acc[m][n], 0, 0, 0);
                acc[m][n] = __builtin_amdgcn_mfma_f32_16x16x32_bf16(ah, bm[n], acc[m][n], 0, 0, 0);
                acc[m][n] = __builtin_amdgcn_mfma_f32_16x16x32_bf16(am, bh[n], acc[m][n], 0, 0, 0);
                acc[m][n] = __builtin_amdgcn_mfma_f32_16x16x32_bf16(ah, bl[n], acc[m][n], 0, 0, 0);
                acc[m][n] = __builtin_amdgcn_mfma_f32_16x16x32_bf16(al, bh[n], acc[m][n], 0, 0, 0);
                acc[m][n] = __builtin_amdgcn_mfma_f32_16x16x32_bf16(am, bm[n], acc[m][n], 0, 0, 0);
            }
        }
        __syncthreads();
    }
    // epilogue: per-wave transpose (32 t at a time) + leaky scan + bitpack
    float* Cw = (float*)smem + w * (32 * 65);
    const float beta1 = *p_beta1, thr1 = *p_thr1;
    const float b1j = b1[j0w + lane];
    float mem = 0.f;
    for (int s = 0; s < 4; ++s) {
        #pragma unroll
        for (int mm = 0; mm < 2; ++mm) {
            int m = s * 2 + mm;
            if (m < 7) {
                #pragma unroll
                for (int n = 0; n < 4; ++n)
                    #pragma unroll
                    for (int r = 0; r < 4; ++r)
                        Cw[(mm * 16 + q * 4 + r) * 65 + n * 16 + n16] = acc[m][n][r];
            }
        }
        int tcnt = (s < 3) ? 32 : 4;
        for (int tt = 0; tt < tcnt; ++tt) {
            float v = Cw[tt * 65 + lane];
            mem = fmaf(beta1, mem, v) + b1j;
            bool pred = (mem - thr1) > 0.f;
            ull mask = __ballot(pred);
            if (pred) mem -= thr1;
            if (lane == 0) {
                int tg = s * 32 + tt;
                s1bits[((size_t)tg * BATCH + b) * 32 + jt * 4 + w] = mask;
            }
        }
    }
}

// ---------------- expand: bits -> bf16 plane for one TCHUNK ----------------
__global__ __launch_bounds__(256) void expand_kernel(
    const ull* __restrict__ bits_t0,       // s1bits + t0*BATCH*32
    unsigned short* __restrict__ plane)
{
    const int row = blockIdx.x;            // t_local*256 + b
    const int tid = threadIdx.x;
    ull word = bits_t0[(size_t)row * 32 + (tid >> 3)];
    unsigned int byte = (unsigned int)(word >> ((tid & 7) * 8)) & 0xFFu;
    unsigned short o8[8];
    #pragma unroll
    for (int e = 0; e < 8; ++e)
        o8[e] = (byte >> e) & 1u ? (unsigned short)0x3F80 : (unsigned short)0;
    *(uint4*)(plane + (size_t)row * 2048 + tid * 8) = *(uint4*)o8;
}

// ---------------- hoisted GEMM (per chunk): X2c = S1c @ W2.T ---------------
// 128-row tiles: grid 640 = 8 xcd x (4 ntl x 20 mt). LDS 40KB.
__global__ __launch_bounds__(256, 2) void xw2_kernel(
    const unsigned short* __restrict__ S1c,
    const unsigned short* __restrict__ Bsplit,
    float* __restrict__ X2c)
{
    __shared__ __align__(16) unsigned short Alds[128 * 64];    // 16 KB
    __shared__ __align__(16) unsigned short Blds[3 * 64 * 64]; // 24 KB
    const int bid = blockIdx.x;
    const int x = bid & 7;
    const int i = bid >> 3;           // 0..79
    const int ntl = i / 20;           // 0..3
    const int mt = i - ntl * 20;      // 0..19 (128-row tile)
    const int n0 = (x * 4 + ntl) << 6;
    const int tid = threadIdx.x, lane = tid & 63, w = tid >> 6;
    const unsigned short* Abase = S1c + ((size_t)mt << 7) * 2048;
    f32x4 acc[2][4] = {};
    for (int c = 0; c < 32; ++c) {
        const int kin = c << 6;
        // stage A 128x64 bf16: linear LDS dest, XOR-swizzled global source
        #pragma unroll
        for (int ii = 0; ii < 4; ++ii) {
            int gi = (ii << 8) + tid;          // granule 0..1023
            int row = gi >> 3, g8 = gi & 7;
            async16(Alds + ((size_t)gi << 3),
                    Abase + (size_t)row * 2048 + kin + ((g8 ^ (row & 7)) << 3));
        }
        #pragma unroll
        for (int term = 0; term < 3; ++term) {
            const unsigned short* Bg = Bsplit + ((size_t)term << 23);
            #pragma unroll
            for (int ii = 0; ii < 2; ++ii) {
                int d = (w << 7) + (ii << 6) + lane;
                int row = d >> 3, g8 = d & 7;
                async16(Blds + (((term << 9) + (w << 7) + (ii << 6)) << 3),
                        Bg + (size_t)(n0 + row) * 4096 + kin + ((g8 ^ (row & 7)) << 3));
            }
        }
        __syncthreads();
        #pragma unroll
        for (int kk = 0; kk < 2; ++kk) {
            const int q = lane >> 4, k16 = (kk << 2) + q;
            bf16x8 af[2];
            #pragma unroll
            for (int ii = 0; ii < 2; ++ii) {
                int ra = (w << 5) + (ii << 4) + (lane & 15);
                af[ii] = *(const bf16x8*)(Alds + (((ra << 3) + (k16 ^ (ra & 7))) << 3));
            }
            #pragma unroll
            for (int term = 0; term < 3; ++term) {
                bf16x8 bfr[4];
                #pragma unroll
                for (int j = 0; j < 4; ++j) {
                    int rb = (j << 4) + (lane & 15);
                    bfr[j] = *(const bf16x8*)(Blds +
                              (((term << 9) + (rb << 3) + (k16 ^ (rb & 7))) << 3));
                }
                #pragma unroll
                for (int ii = 0; ii < 2; ++ii)
                    #pragma unroll
                    for (int j = 0; j < 4; ++j)
                        acc[ii][j] = __builtin_amdgcn_mfma_f32_16x16x32_bf16(
                            af[ii], bfr[j], acc[ii][j], 0, 0, 0);
            }
        }
        __syncthreads();
    }
    float* Xp = X2c + ((size_t)mt << 7) * 2048;
    #pragma unroll
    for (int ii = 0; ii < 2; ++ii) {
        int rg = (w << 5) + (ii << 4) + ((lane >> 4) << 2);
        #pragma unroll
        for (int j = 0; j < 4; ++j) {
            int cg = n0 + (j << 4) + (lane & 15);
            #pragma unroll
            for (int r = 0; r < 4; ++r)
                Xp[(size_t)(rg + r) * 2048 + cg] = acc[ii][j][r];
        }
    }
}

// ---------------- fused per-step: V GEMM + arrival/spin + full-parallel fin -
// grid 256 = 32 nt x 8 ks, all co-resident (56KB LDS -> 2 blocks/CU cap).
// GEMM part verbatim from the proven round-2 vgemm. Then: fence + arrive on
// monotonic done[nt]; spin (s_sleep) until all 8 ks-blocks of this nt have
// arrived; then EACH block finishes its own 32b x 64j slice with the exact
// l2fin math (bit-identical). Cpart partials for nt live on XCD nt%8 (bid%8
// == nt%8 for both writer and reader) -> L2-local round-trip.
__global__ __launch_bounds__(256, 2) void vstep_kernel(
    const unsigned short* __restrict__ spk,    // [256][2048] bf16 {0,1}
    const unsigned short* __restrict__ Bsplit,
    float* __restrict__ Cpart,
    const float* __restrict__ X2t, const float* __restrict__ b2,
    float* __restrict__ mem_r, float* __restrict__ ahp,
    unsigned short* __restrict__ spk_out,
    ull* __restrict__ srbits_t,                // srbits + t*BATCH*32
    unsigned int* __restrict__ done, unsigned int expected,  // = 8*(t+1)
    const float* __restrict__ p_beta_r, const float* __restrict__ p_thr_r,
    const float* __restrict__ p_back_beta, const float* __restrict__ p_alpha)
{
    __shared__ __align__(16) unsigned short Alds[256 * 64];    // 32 KB
    __shared__ __align__(16) unsigned short Blds[3 * 64 * 64]; // 24 KB
    const int bid = blockIdx.x;
    const int nt = bid & 31, ks = bid >> 5;
    const int n0 = nt << 6;
    const int tid = threadIdx.x, lane = tid & 63, w = tid >> 6;
    f32x4 acc[4][4] = {};
    for (int c = 0; c < 4; ++c) {
        const int kin = (ks << 8) + (c << 6);
        #pragma unroll
        for (int ii = 0; ii < 8; ++ii) {
            int gi = (ii << 8) + tid;
            int row = gi >> 3, g8 = gi & 7;
            async16(Alds + ((size_t)gi << 3),
                    spk + (size_t)row * 2048 + kin + ((g8 ^ (row & 7)) << 3));
        }
        #pragma unroll
        for (int term = 0; term < 3; ++term) {
            const unsigned short* Bg = Bsplit + ((size_t)term << 23);
            #pragma unroll
            for (int ii = 0; ii < 2; ++ii) {
                int d = (w << 7) + (ii << 6) + lane;
                int row = d >> 3, g8 = d & 7;
                // V region: column offset 2048 within the 4096-stride row
                async16(Blds + (((term << 9) + (w << 7) + (ii << 6)) << 3),
                        Bg + (size_t)(n0 + row) * 4096 + 2048 + kin + ((g8 ^ (row & 7)) << 3));
            }
        }
        __syncthreads();
        #pragma unroll
        for (int kk = 0; kk < 2; ++kk) {
            const int q = lane >> 4, k16 = (kk << 2) + q;
            bf16x8 af[4];
            #pragma unroll
            for (int ii = 0; ii < 4; ++ii) {
                int ra = (w << 6) + (ii << 4) + (lane & 15);
                af[ii] = *(const bf16x8*)(Alds + (((ra << 3) + (k16 ^ (ra & 7))) << 3));
            }
            #pragma unroll
            for (int term = 0; term < 3; ++term) {
                bf16x8 bfr[4];
                #pragma unroll
                for (int j = 0; j < 4; ++j) {
                    int rb = (j << 4) + (lane & 15);
                    bfr[j] = *(const bf16x8*)(Blds +
                              (((term << 9) + (rb << 3) + (k16 ^ (rb & 7))) << 3));
                }
                #pragma unroll
                for (int ii = 0; ii < 4; ++ii)
                    #pragma unroll
                    for (int j = 0; j < 4; ++j)
                        acc[ii][j] = __builtin_amdgcn_mfma_f32_16x16x32_bf16(
                            af[ii], bfr[j], acc[ii][j], 0, 0, 0);
            }
        }
        __syncthreads();
    }
    {
        float* Cp = Cpart + ((size_t)ks << 19);
        #pragma unroll
        for (int ii = 0; ii < 4; ++ii) {
            int rg = (w << 6) + (ii << 4) + ((lane >> 4) << 2);
            #pragma unroll
            for (int j = 0; j < 4; ++j) {
                int cg = n0 + (j << 4) + (lane & 15);
                #pragma unroll
                for (int r = 0; r < 4; ++r)
                    Cp[(size_t)(rg + r) * 2048 + cg] = acc[ii][j][r];
            }
        }
    }
    // ---- arrival + spin: wait for all 8 ks-blocks of this nt --------------
    __syncthreads();                 // drains Cpart stores (barrier vmcnt 0)
    if (tid == 0) {
        __threadfence();             // release partials to device scope
        atomicAdd(&done[nt], 1u);
        while (atomicAdd(&done[nt], 0u) < expected)
            __builtin_amdgcn_s_sleep(2);
    }
    __syncthreads();
    __threadfence();                 // acquire: see other blocks' partials
    // ---- fin: this block's 32b x 64j slice (math identical to l2fin) ------
    const float beta_r = *p_beta_r, thr_r = *p_thr_r;
    const float bb = *p_back_beta, al = *p_alpha;
    const int jj = n0 + lane;
    const float b2j = b2[jj];
    #pragma unroll
    for (int u = 0; u < 8; ++u) {
        int b = (ks << 5) + (w << 3) + u;
        size_t cidx = ((size_t)b << 11) + jj;
        float x = 0.f;
        #pragma unroll
        for (int p = 0; p < VKS; ++p) x += Cpart[((size_t)p << 19) + cidx];
        float cur = x + X2t[cidx] + b2j;
        float m = fmaf(beta_r, mem_r[cidx], cur) - ahp[cidx];
        bool pred = (m - thr_r) > 0.f;
        ull mask = __ballot(pred);
        float s = pred ? 1.f : 0.f;
        if (pred) m -= thr_r;
        mem_r[cidx] = m;
        ahp[cidx] = fmaf(bb, ahp[cidx], al * s);
        spk_out[cidx] = pred ? (unsigned short)0x3F80 : (unsigned short)0;
        if (lane == 0) srbits_t[((size_t)b << 5) + nt] = mask;
    }
}

// ---------------- deferred layer 3: all 100 steps in one launch ------------
// grid 256 (b). Bits staged in LDS; W3 in registers (2 passes x 10 outputs);
// verified in round 3 (absmax 0).
__global__ __launch_bounds__(256) void w3out_kernel(
    const ull* __restrict__ srbits, const float* __restrict__ W3,
    const float* __restrict__ b3, float* __restrict__ out,
    const float* __restrict__ p_beta2, const float* __restrict__ p_thr2)
{
    __shared__ ull bitsLDS[T_STEPS * 32];   // 25.6 KB
    __shared__ float red[4][10];
    const int b = blockIdx.x, tid = threadIdx.x, lane = tid & 63, wv = tid >> 6;
    for (int i = tid; i < T_STEPS * 32; i += 256)
        bitsLDS[i] = srbits[((size_t)(i >> 5) * BATCH + b) * 32 + (i & 31)];
    __syncthreads();
    const float beta2 = *p_beta2, thr2 = *p_thr2;
    for (int pass = 0; pass < 2; ++pass) {
        float w8[10][8];
        #pragma unroll
        for (int o = 0; o < 10; ++o) {
            const float4* wp = (const float4*)(W3 + (size_t)(pass * 10 + o) * 2048 + tid * 8);
            float4 a = wp[0], c = wp[1];
            w8[o][0] = a.x; w8[o][1] = a.y; w8[o][2] = a.z; w8[o][3] = a.w;
            w8[o][4] = c.x; w8[o][5] = c.y; w8[o][6] = c.z; w8[o][7] = c.w;
        }
        float m2 = 0.f;
        for (int t = 0; t < T_STEPS; ++t) {
            ull word = bitsLDS[(t << 5) + (tid >> 3)];
            unsigned int byte = (unsigned int)(word >> ((tid & 7) * 8)) & 0xFFu;
            float po[10];
            #pragma unroll
            for (int o = 0; o < 10; ++o) {
                float v = 0.f;
                #pragma unroll
                for (int e = 0; e < 8; ++e)
                    v += ((byte >> e) & 1u) ? w8[o][e] : 0.f;
                #pragma unroll
                for (int msk = 32; msk > 0; msk >>= 1)
                    v += __shfl_xor(v, msk, 64);
                po[o] = v;
            }
            if (lane == 0) {
                #pragma unroll
                for (int o = 0; o < 10; ++o) red[wv][o] = po[o];
            }
            __syncthreads();
            if (tid < 10) {
                float cur = red[0][tid] + red[1][tid] + red[2][tid] + red[3][tid]
                          + b3[pass * 10 + tid];
                float m = fmaf(beta2, m2, cur);
                bool pred = (m - thr2) > 0.f;
                float s2 = pred ? 1.f : 0.f;
                if (pred) m -= thr2;
                m2 = m;
                out[((size_t)t * BATCH + b) * NOUT + pass * 10 + tid] = s2;
            }
            __syncthreads();
        }
    }
}

extern "C" void kernel_launch(void* const* d_in, const int* in_sizes, int n_in,
                              void* d_out, int out_size, void* d_ws, size_t ws_size,
                              hipStream_t stream)
{
    const float* data   = (const float*)d_in[0];
    const float* W1     = (const float*)d_in[1];
    const float* b1     = (const float*)d_in[2];
    const float* W2     = (const float*)d_in[3];
    const float* b2     = (const float*)d_in[4];
    const float* V      = (const float*)d_in[5];
    const float* W3     = (const float*)d_in[6];
    const float* b3     = (const float*)d_in[7];
    const float* beta1  = (const float*)d_in[8];
    const float* thr1   = (const float*)d_in[9];
    const float* beta_r = (const float*)d_in[10];
    const float* thr_r  = (const float*)d_in[11];
    const float* back_beta = (const float*)d_in[12];
    const float* alpha  = (const float*)d_in[13];
    const float* beta2  = (const float*)d_in[14];
    const float* thr2   = (const float*)d_in[15];
    float* out = (float*)d_out;
    (void)in_sizes; (void)n_in; (void)out_size; (void)ws_size;

    char* p = (char*)d_ws;
    auto carve = [&](size_t bytes) {
        char* r = p; p += (bytes + 255) & ~(size_t)255; return r;
    };
    // total carved: ~117 MB
    ull* s1bits = (ull*)carve((size_t)T_STEPS*BATCH*32*8);                   // 6.55 MB
    ull* srbits = (ull*)carve((size_t)T_STEPS*BATCH*32*8);                   // 6.55 MB
    unsigned short* spk0 = (unsigned short*)carve((size_t)BATCH*H2*2);       // 1 MB
    unsigned short* spk1 = (unsigned short*)carve((size_t)BATCH*H2*2);       // 1 MB
    float* mem_r = (float*)carve((size_t)BATCH*H2*4);                        // 2.1 MB
    float* ahp   = (float*)carve((size_t)BATCH*H2*4);                        // 2.1 MB
    unsigned int* done = (unsigned int*)carve(32 * sizeof(unsigned int));
    unsigned short* Bsplit = (unsigned short*)carve((size_t)3*2048*4096*2);  // 50.3 MB
    // union region: S1bf chunk plane (10.5 MB, live during expand+xw2 only)
    // and Cpart (16.8 MB, live during step loop only). Sequential stream.
    char* uni = carve((size_t)VKS*BATCH*H2*4);                               // 16.8 MB
    unsigned short* S1c = (unsigned short*)uni;
    float* Cpart = (float*)uni;
    float* X2c = (float*)carve((size_t)TCHUNK*BATCH*H2*4);                   // 21 MB
    unsigned short* W1f = (unsigned short*)carve((size_t)3*88*2048*8*2);     // 8.65 MB

    hipMemsetAsync(spk0, 0, (size_t)BATCH*H2*2, stream);
    hipMemsetAsync(mem_r, 0, (size_t)BATCH*H2*4, stream);
    hipMemsetAsync(ahp,  0, (size_t)BATCH*H2*4, stream);
    hipMemsetAsync(done, 0, 32 * sizeof(unsigned int), stream);

    split_kernel<<<(2048*4096)/256, 256, 0, stream>>>(W2, V, Bsplit);
    w1split_kernel<<<704, 256, 0, stream>>>(W1, W1f);
    l1m_kernel<<<2048, 256, 0, stream>>>(data, W1f, b1, beta1, thr1, s1bits);

    unsigned short* spk[2] = {spk0, spk1};
    for (int ck = 0; ck < T_STEPS / TCHUNK; ++ck) {
        const int t0 = ck * TCHUNK;
        expand_kernel<<<TCHUNK*BATCH, 256, 0, stream>>>(
            s1bits + (size_t)t0*BATCH*32, S1c);
        xw2_kernel<<<8*4*2*TCHUNK, 256, 0, stream>>>(S1c, Bsplit, X2c);
        for (int tt = 0; tt < TCHUNK; ++tt) {
            const int t = t0 + tt;
            vstep_kernel<<<256, 256, 0, stream>>>(
                spk[t & 1], Bsplit, Cpart, X2c + (size_t)tt*BATCH*H2, b2,
                mem_r, ahp, spk[(t + 1) & 1], srbits + (size_t)t*BATCH*32,
                done, 8u*(unsigned)(t + 1),
                beta_r, thr_r, back_beta, alpha);
        }
    }
    w3out_kernel<<<256, 256, 0, stream>>>(srbits, W3, b3, out, beta2, thr2);
}

// Round 7
// 4334.451 us; speedup vs baseline: 1.6208x; 1.6208x over previous
//
#include <hip/hip_runtime.h>
#include <hip/hip_bf16.h>
#include <cstdint>

#define T_STEPS 100
#define BATCH 256
#define NIN 700
#define H1 2048
#define H2 2048
#define NOUT 20
#define TCHUNK 10       // timesteps per hoisted-GEMM chunk (10 chunks)

typedef __attribute__((ext_vector_type(8))) short bf16x8;
typedef __attribute__((ext_vector_type(4))) float f32x4;
typedef unsigned long long ull;

__device__ __forceinline__ void async16(void* lds, const void* g) {
    __builtin_amdgcn_global_load_lds(
        (const __attribute__((address_space(1))) unsigned int*)g,
        (__attribute__((address_space(3))) unsigned int*)lds, 16, 0, 0);
}

__device__ __forceinline__ unsigned short f2bf(float x) {
    __hip_bfloat16 h = __float2bfloat16(x);
    return *(unsigned short*)&h;
}
__device__ __forceinline__ float bf2f(unsigned short u) {
    __hip_bfloat16 h = *(__hip_bfloat16*)&u;
    return __bfloat162float(h);
}

// ---------------- split W2|V into bf16 hi/mid/lo, layout [term][j][4096k] ----
// k<2048 = W2 row, k>=2048 = V row.
__global__ __launch_bounds__(256) void split_kernel(
    const float* __restrict__ W2, const float* __restrict__ V,
    unsigned short* __restrict__ Bsplit)
{
    const size_t D = (size_t)2048 * 4096;
    size_t i = (size_t)blockIdx.x * 256 + threadIdx.x;
    int j = (int)(i >> 12), k = (int)(i & 4095);
    float w = (k < 2048) ? W2[(size_t)j * 2048 + k] : V[(size_t)j * 2048 + (k - 2048)];
    unsigned short h = f2bf(w);
    float r1 = w - bf2f(h);
    unsigned short m = f2bf(r1);
    float r2 = r1 - bf2f(m);
    unsigned short l = f2bf(r2);
    Bsplit[i] = h;
    Bsplit[D + i] = m;
    Bsplit[2 * D + i] = l;
}

// ---------------- split W1 into granule-major bf16 planes ------------------
// W1f[term][g 0..87][j 0..2047][8] ; k = g*8+e, zero-padded k>=700.
__global__ __launch_bounds__(256) void w1split_kernel(
    const float* __restrict__ W1, unsigned short* __restrict__ W1f)
{
    const size_t P = (size_t)88 * 2048 * 8;   // elems per term
    int id = blockIdx.x * 256 + threadIdx.x;  // 0..180223
    int g = id >> 11, j = id & 2047;
    unsigned short h8[8], m8[8], l8[8];
    #pragma unroll
    for (int e = 0; e < 8; ++e) {
        int k = g * 8 + e;
        float v = (k < NIN) ? W1[(size_t)j * NIN + k] : 0.f;
        unsigned short h = f2bf(v); float r1 = v - bf2f(h);
        unsigned short m = f2bf(r1); float r2 = r1 - bf2f(m);
        h8[e] = h; m8[e] = m; l8[e] = f2bf(r2);
    }
    size_t base = (((size_t)g * 2048) + j) * 8;
    *(uint4*)(W1f + base)         = *(uint4*)h8;
    *(uint4*)(W1f + P + base)     = *(uint4*)m8;
    *(uint4*)(W1f + 2 * P + base) = *(uint4*)l8;
}

// ---------------- layer 1 via MFMA: x@W1.T (6-term bf16) + scan + bitpack ----
// grid 2048 = 8 jt (bid&7, XCD-locality) x 256 b. Block 256 thr / 4 waves.
__global__ __launch_bounds__(256) void l1m_kernel(
    const float* __restrict__ data, const unsigned short* __restrict__ W1f,
    const float* __restrict__ b1,
    const float* __restrict__ p_beta1, const float* __restrict__ p_thr1,
    ull* __restrict__ s1bits)
{
    __shared__ __align__(16) char smem[33280];  // union: Af 21.5KB | Cw 4x8.3KB
    unsigned short* Af = (unsigned short*)smem; // [3 term][4 g][112 t][8]
    const int tid = threadIdx.x, lane = tid & 63, w = tid >> 6;
    const int n16 = lane & 15, q = lane >> 4;
    const int jt = blockIdx.x & 7, b = blockIdx.x >> 3;
    const int j0w = jt * 256 + w * 64;
    const float* xb = data + (size_t)b * (NIN * T_STEPS);
    const size_t P = (size_t)88 * 2048 * 8;

    f32x4 acc[7][4] = {};
    for (int c = 0; c < 22; ++c) {
        const int kbase = c * 32;
        for (int it = tid; it < 448; it += 256) {
            int g = it / 112, t = it - g * 112;
            unsigned short h8[8], m8[8], l8[8];
            #pragma unroll
            for (int e = 0; e < 8; ++e) {
                int k = kbase + g * 8 + e;
                float v = (t < T_STEPS && k < NIN) ? xb[(size_t)k * T_STEPS + t] : 0.f;
                unsigned short h = f2bf(v); float r1 = v - bf2f(h);
                unsigned short m = f2bf(r1); float r2 = r1 - bf2f(m);
                h8[e] = h; m8[e] = m; l8[e] = f2bf(r2);
            }
            unsigned short* dst = Af + g * 896 + t * 8;
            *(uint4*)(dst)        = *(uint4*)h8;
            *(uint4*)(dst + 3584) = *(uint4*)m8;
            *(uint4*)(dst + 7168) = *(uint4*)l8;
        }
        __syncthreads();
        bf16x8 bh[4], bm[4], bl[4];
        const size_t gq = (size_t)(c * 4 + q);
        #pragma unroll
        for (int n = 0; n < 4; ++n) {
            size_t off = (gq * 2048 + (size_t)(j0w + n * 16 + n16)) * 8;
            bh[n] = *(const bf16x8*)(W1f + off);
            bm[n] = *(const bf16x8*)(W1f + P + off);
            bl[n] = *(const bf16x8*)(W1f + 2 * P + off);
        }
        #pragma unroll
        for (int m = 0; m < 7; ++m) {
            const unsigned short* ap = Af + q * 896 + (m * 16 + n16) * 8;
            bf16x8 ah = *(const bf16x8*)(ap);
            bf16x8 am = *(const bf16x8*)(ap + 3584);
            bf16x8 al = *(const bf16x8*)(ap + 7168);
            #pragma unroll
            for (int n = 0; n < 4; ++n) {
                acc[m][n] = __builtin_amdgcn_mfma_f32_16x16x32_bf16(ah, bh[n], acc[m][n], 0, 0, 0);
                acc[m][n] = __builtin_amdgcn_mfma_f32_16x16x32_bf16(ah, bm[n], acc[m][n], 0, 0, 0);
                acc[m][n] = __builtin_amdgcn_mfma_f32_16x16x32_bf16(am, bh[n], acc[m][n], 0, 0, 0);
                acc[m][n] = __builtin_amdgcn_mfma_f32_16x16x32_bf16(ah, bl[n], acc[m][n], 0, 0, 0);
                acc[m][n] = __builtin_amdgcn_mfma_f32_16x16x32_bf16(al, bh[n], acc[m][n], 0, 0, 0);
                acc[m][n] = __builtin_amdgcn_mfma_f32_16x16x32_bf16(am, bm[n], acc[m][n], 0, 0, 0);
            }
        }
        __syncthreads();
    }
    // epilogue: per-wave transpose (32 t at a time) + leaky scan + bitpack
    float* Cw = (float*)smem + w * (32 * 65);
    const float beta1 = *p_beta1, thr1 = *p_thr1;
    const float b1j = b1[j0w + lane];
    float mem = 0.f;
    for (int s = 0; s < 4; ++s) {
        #pragma unroll
        for (int mm = 0; mm < 2; ++mm) {
            int m = s * 2 + mm;
            if (m < 7) {
                #pragma unroll
                for (int n = 0; n < 4; ++n)
                    #pragma unroll
                    for (int r = 0; r < 4; ++r)
                        Cw[(mm * 16 + q * 4 + r) * 65 + n * 16 + n16] = acc[m][n][r];
            }
        }
        int tcnt = (s < 3) ? 32 : 4;
        for (int tt = 0; tt < tcnt; ++tt) {
            float v = Cw[tt * 65 + lane];
            mem = fmaf(beta1, mem, v) + b1j;
            bool pred = (mem - thr1) > 0.f;
            ull mask = __ballot(pred);
            if (pred) mem -= thr1;
            if (lane == 0) {
                int tg = s * 32 + tt;
                s1bits[((size_t)tg * BATCH + b) * 32 + jt * 4 + w] = mask;
            }
        }
    }
}

// ---------------- expand: bits -> bf16 plane for one TCHUNK ----------------
__global__ __launch_bounds__(256) void expand_kernel(
    const ull* __restrict__ bits_t0,       // s1bits + t0*BATCH*32
    unsigned short* __restrict__ plane)
{
    const int row = blockIdx.x;            // t_local*256 + b
    const int tid = threadIdx.x;
    ull word = bits_t0[(size_t)row * 32 + (tid >> 3)];
    unsigned int byte = (unsigned int)(word >> ((tid & 7) * 8)) & 0xFFu;
    unsigned short o8[8];
    #pragma unroll
    for (int e = 0; e < 8; ++e)
        o8[e] = (byte >> e) & 1u ? (unsigned short)0x3F80 : (unsigned short)0;
    *(uint4*)(plane + (size_t)row * 2048 + tid * 8) = *(uint4*)o8;
}

// ---------------- hoisted GEMM (per chunk): X2c = S1c @ W2.T ---------------
// 128-row tiles: grid 640 = 8 xcd x (4 ntl x 20 mt). LDS 40KB.
__global__ __launch_bounds__(256, 2) void xw2_kernel(
    const unsigned short* __restrict__ S1c,
    const unsigned short* __restrict__ Bsplit,
    float* __restrict__ X2c)
{
    __shared__ __align__(16) unsigned short Alds[128 * 64];    // 16 KB
    __shared__ __align__(16) unsigned short Blds[3 * 64 * 64]; // 24 KB
    const int bid = blockIdx.x;
    const int x = bid & 7;
    const int i = bid >> 3;           // 0..79
    const int ntl = i / 20;           // 0..3
    const int mt = i - ntl * 20;      // 0..19 (128-row tile)
    const int n0 = (x * 4 + ntl) << 6;
    const int tid = threadIdx.x, lane = tid & 63, w = tid >> 6;
    const unsigned short* Abase = S1c + ((size_t)mt << 7) * 2048;
    f32x4 acc[2][4] = {};
    for (int c = 0; c < 32; ++c) {
        const int kin = c << 6;
        // stage A 128x64 bf16: linear LDS dest, XOR-swizzled global source
        #pragma unroll
        for (int ii = 0; ii < 4; ++ii) {
            int gi = (ii << 8) + tid;          // granule 0..1023
            int row = gi >> 3, g8 = gi & 7;
            async16(Alds + ((size_t)gi << 3),
                    Abase + (size_t)row * 2048 + kin + ((g8 ^ (row & 7)) << 3));
        }
        #pragma unroll
        for (int term = 0; term < 3; ++term) {
            const unsigned short* Bg = Bsplit + ((size_t)term << 23);
            #pragma unroll
            for (int ii = 0; ii < 2; ++ii) {
                int d = (w << 7) + (ii << 6) + lane;
                int row = d >> 3, g8 = d & 7;
                async16(Blds + (((term << 9) + (w << 7) + (ii << 6)) << 3),
                        Bg + (size_t)(n0 + row) * 4096 + kin + ((g8 ^ (row & 7)) << 3));
            }
        }
        __syncthreads();
        #pragma unroll
        for (int kk = 0; kk < 2; ++kk) {
            const int q = lane >> 4, k16 = (kk << 2) + q;
            bf16x8 af[2];
            #pragma unroll
            for (int ii = 0; ii < 2; ++ii) {
                int ra = (w << 5) + (ii << 4) + (lane & 15);
                af[ii] = *(const bf16x8*)(Alds + (((ra << 3) + (k16 ^ (ra & 7))) << 3));
            }
            #pragma unroll
            for (int term = 0; term < 3; ++term) {
                bf16x8 bfr[4];
                #pragma unroll
                for (int j = 0; j < 4; ++j) {
                    int rb = (j << 4) + (lane & 15);
                    bfr[j] = *(const bf16x8*)(Blds +
                              (((term << 9) + (rb << 3) + (k16 ^ (rb & 7))) << 3));
                }
                #pragma unroll
                for (int ii = 0; ii < 2; ++ii)
                    #pragma unroll
                    for (int j = 0; j < 4; ++j)
                        acc[ii][j] = __builtin_amdgcn_mfma_f32_16x16x32_bf16(
                            af[ii], bfr[j], acc[ii][j], 0, 0, 0);
            }
        }
        __syncthreads();
    }
    float* Xp = X2c + ((size_t)mt << 7) * 2048;
    #pragma unroll
    for (int ii = 0; ii < 2; ++ii) {
        int rg = (w << 5) + (ii << 4) + ((lane >> 4) << 2);
        #pragma unroll
        for (int j = 0; j < 4; ++j) {
            int cg = n0 + (j << 4) + (lane & 15);
            #pragma unroll
            for (int r = 0; r < 4; ++r)
                Xp[(size_t)(rg + r) * 2048 + cg] = acc[ii][j][r];
        }
    }
}

// ---------------- fused per-step: M-SPLIT full-K V GEMM + block-local fin --
// grid 256 = 8 mblk (32 b-rows) x 32 nt (64 j). Each block computes the FULL
// K=2048x3 for its 32x64 tile -> the neuron update is entirely block-local:
// acc -> LDS transpose -> exact l2fin math -> spk plane + srbits. No Cpart,
// no cross-block sync. bid = mblk*32+nt => bid%8 == nt%8: all 8 m-blocks of
// an nt share an XCD, so the 786KB B panel is read 1x from L3 + 7x from L2.
__global__ __launch_bounds__(256) void vfull_kernel(
    const unsigned short* __restrict__ spk,    // [256][2048] bf16 {0,1}
    const unsigned short* __restrict__ Bsplit,
    const float* __restrict__ X2t, const float* __restrict__ b2,
    float* __restrict__ mem_r, float* __restrict__ ahp,
    unsigned short* __restrict__ spk_out,
    ull* __restrict__ srbits_t,                // srbits + t*BATCH*32
    const float* __restrict__ p_beta_r, const float* __restrict__ p_thr_r,
    const float* __restrict__ p_back_beta, const float* __restrict__ p_alpha)
{
    __shared__ __align__(16) unsigned short Alds[32 * 64];     // 4 KB
    __shared__ __align__(16) unsigned short Blds[3 * 64 * 64]; // 24 KB
    __shared__ float Cl[32 * 65];                              // 8.32 KB
    const int bid = blockIdx.x;
    const int nt = bid & 31, mblk = bid >> 5;
    const int n0 = nt << 6, b0 = mblk << 5;
    const int tid = threadIdx.x, lane = tid & 63, w = tid >> 6;
    const int rw = w >> 1;              // row-tile (16 rows): 0..1
    const int jt0 = (w & 1) << 1;       // col-tile pair base: 0 or 2
    f32x4 acc[2] = {};
    for (int c = 0; c < 32; ++c) {
        const int kin = c << 6;
        {   // stage A 32x64: 1 granule/thread
            int row = tid >> 3, g8 = tid & 7;
            async16(Alds + ((size_t)tid << 3),
                    spk + (size_t)(b0 + row) * 2048 + kin + ((g8 ^ (row & 7)) << 3));
        }
        #pragma unroll
        for (int term = 0; term < 3; ++term) {
            const unsigned short* Bg = Bsplit + ((size_t)term << 23);
            #pragma unroll
            for (int ii = 0; ii < 2; ++ii) {
                int d = (w << 7) + (ii << 6) + lane;
                int row = d >> 3, g8 = d & 7;
                // V region: column offset 2048 within the 4096-stride row
                async16(Blds + (((term << 9) + (w << 7) + (ii << 6)) << 3),
                        Bg + (size_t)(n0 + row) * 4096 + 2048 + kin + ((g8 ^ (row & 7)) << 3));
            }
        }
        __syncthreads();
        #pragma unroll
        for (int kk = 0; kk < 2; ++kk) {
            const int q = lane >> 4, k16 = (kk << 2) + q;
            int ra = (rw << 4) + (lane & 15);
            bf16x8 af = *(const bf16x8*)(Alds + (((ra << 3) + (k16 ^ (ra & 7))) << 3));
            #pragma unroll
            for (int term = 0; term < 3; ++term) {
                #pragma unroll
                for (int j = 0; j < 2; ++j) {
                    int rb = ((jt0 + j) << 4) + (lane & 15);
                    bf16x8 bfr = *(const bf16x8*)(Blds +
                              (((term << 9) + (rb << 3) + (k16 ^ (rb & 7))) << 3));
                    acc[j] = __builtin_amdgcn_mfma_f32_16x16x32_bf16(af, bfr, acc[j], 0, 0, 0);
                }
            }
        }
        __syncthreads();
    }
    // C tile -> LDS (row-major, pad 65)
    {
        const int q = lane >> 4;
        #pragma unroll
        for (int j = 0; j < 2; ++j)
            #pragma unroll
            for (int r = 0; r < 4; ++r)
                Cl[((rw << 4) + (q << 2) + r) * 65 + ((jt0 + j) << 4) + (lane & 15)] = acc[j][r];
    }
    __syncthreads();
    // fin: wave w handles rows w*8..w*8+7; lane = j within nt (ballot = word)
    const float beta_r = *p_beta_r, thr_r = *p_thr_r;
    const float bb = *p_back_beta, al = *p_alpha;
    const int jg = n0 + lane;
    const float b2j = b2[jg];
    #pragma unroll
    for (int u = 0; u < 8; ++u) {
        int row = (w << 3) + u;
        int b = b0 + row;
        size_t cidx = ((size_t)b << 11) + jg;
        float x = Cl[row * 65 + lane];
        float cur = x + X2t[cidx] + b2j;
        float m = fmaf(beta_r, mem_r[cidx], cur) - ahp[cidx];
        bool pred = (m - thr_r) > 0.f;
        ull mask = __ballot(pred);
        float s = pred ? 1.f : 0.f;
        if (pred) m -= thr_r;
        mem_r[cidx] = m;
        ahp[cidx] = fmaf(bb, ahp[cidx], al * s);
        spk_out[cidx] = pred ? (unsigned short)0x3F80 : (unsigned short)0;
        if (lane == 0) srbits_t[((size_t)b << 5) + nt] = mask;
    }
}

// ---------------- deferred layer 3: all 100 steps in one launch ------------
// grid 256 (b). Bits staged in LDS; W3 in registers (2 passes x 10 outputs);
// verified in round 3 (absmax 0).
__global__ __launch_bounds__(256) void w3out_kernel(
    const ull* __restrict__ srbits, const float* __restrict__ W3,
    const float* __restrict__ b3, float* __restrict__ out,
    const float* __restrict__ p_beta2, const float* __restrict__ p_thr2)
{
    __shared__ ull bitsLDS[T_STEPS * 32];   // 25.6 KB
    __shared__ float red[4][10];
    const int b = blockIdx.x, tid = threadIdx.x, lane = tid & 63, wv = tid >> 6;
    for (int i = tid; i < T_STEPS * 32; i += 256)
        bitsLDS[i] = srbits[((size_t)(i >> 5) * BATCH + b) * 32 + (i & 31)];
    __syncthreads();
    const float beta2 = *p_beta2, thr2 = *p_thr2;
    for (int pass = 0; pass < 2; ++pass) {
        float w8[10][8];
        #pragma unroll
        for (int o = 0; o < 10; ++o) {
            const float4* wp = (const float4*)(W3 + (size_t)(pass * 10 + o) * 2048 + tid * 8);
            float4 a = wp[0], c = wp[1];
            w8[o][0] = a.x; w8[o][1] = a.y; w8[o][2] = a.z; w8[o][3] = a.w;
            w8[o][4] = c.x; w8[o][5] = c.y; w8[o][6] = c.z; w8[o][7] = c.w;
        }
        float m2 = 0.f;
        for (int t = 0; t < T_STEPS; ++t) {
            ull word = bitsLDS[(t << 5) + (tid >> 3)];
            unsigned int byte = (unsigned int)(word >> ((tid & 7) * 8)) & 0xFFu;
            float po[10];
            #pragma unroll
            for (int o = 0; o < 10; ++o) {
                float v = 0.f;
                #pragma unroll
                for (int e = 0; e < 8; ++e)
                    v += ((byte >> e) & 1u) ? w8[o][e] : 0.f;
                #pragma unroll
                for (int msk = 32; msk > 0; msk >>= 1)
                    v += __shfl_xor(v, msk, 64);
                po[o] = v;
            }
            if (lane == 0) {
                #pragma unroll
                for (int o = 0; o < 10; ++o) red[wv][o] = po[o];
            }
            __syncthreads();
            if (tid < 10) {
                float cur = red[0][tid] + red[1][tid] + red[2][tid] + red[3][tid]
                          + b3[pass * 10 + tid];
                float m = fmaf(beta2, m2, cur);
                bool pred = (m - thr2) > 0.f;
                float s2 = pred ? 1.f : 0.f;
                if (pred) m -= thr2;
                m2 = m;
                out[((size_t)t * BATCH + b) * NOUT + pass * 10 + tid] = s2;
            }
            __syncthreads();
        }
    }
}

extern "C" void kernel_launch(void* const* d_in, const int* in_sizes, int n_in,
                              void* d_out, int out_size, void* d_ws, size_t ws_size,
                              hipStream_t stream)
{
    const float* data   = (const float*)d_in[0];
    const float* W1     = (const float*)d_in[1];
    const float* b1     = (const float*)d_in[2];
    const float* W2     = (const float*)d_in[3];
    const float* b2     = (const float*)d_in[4];
    const float* V      = (const float*)d_in[5];
    const float* W3     = (const float*)d_in[6];
    const float* b3     = (const float*)d_in[7];
    const float* beta1  = (const float*)d_in[8];
    const float* thr1   = (const float*)d_in[9];
    const float* beta_r = (const float*)d_in[10];
    const float* thr_r  = (const float*)d_in[11];
    const float* back_beta = (const float*)d_in[12];
    const float* alpha  = (const float*)d_in[13];
    const float* beta2  = (const float*)d_in[14];
    const float* thr2   = (const float*)d_in[15];
    float* out = (float*)d_out;
    (void)in_sizes; (void)n_in; (void)out_size; (void)ws_size;

    char* p = (char*)d_ws;
    auto carve = [&](size_t bytes) {
        char* r = p; p += (bytes + 255) & ~(size_t)255; return r;
    };
    // total carved: ~117 MB
    ull* s1bits = (ull*)carve((size_t)T_STEPS*BATCH*32*8);                   // 6.55 MB
    ull* srbits = (ull*)carve((size_t)T_STEPS*BATCH*32*8);                   // 6.55 MB
    unsigned short* spk0 = (unsigned short*)carve((size_t)BATCH*H2*2);       // 1 MB
    unsigned short* spk1 = (unsigned short*)carve((size_t)BATCH*H2*2);       // 1 MB
    float* mem_r = (float*)carve((size_t)BATCH*H2*4);                        // 2.1 MB
    float* ahp   = (float*)carve((size_t)BATCH*H2*4);                        // 2.1 MB
    unsigned short* Bsplit = (unsigned short*)carve((size_t)3*2048*4096*2);  // 50.3 MB
    // union region: S1bf chunk plane (10.5 MB, live during expand+xw2 only).
    char* uni = carve((size_t)TCHUNK*BATCH*H1*2);                            // 10.5 MB
    unsigned short* S1c = (unsigned short*)uni;
    float* X2c = (float*)carve((size_t)TCHUNK*BATCH*H2*4);                   // 21 MB
    unsigned short* W1f = (unsigned short*)carve((size_t)3*88*2048*8*2);     // 8.65 MB

    hipMemsetAsync(spk0, 0, (size_t)BATCH*H2*2, stream);
    hipMemsetAsync(mem_r, 0, (size_t)BATCH*H2*4, stream);
    hipMemsetAsync(ahp,  0, (size_t)BATCH*H2*4, stream);

    split_kernel<<<(2048*4096)/256, 256, 0, stream>>>(W2, V, Bsplit);
    w1split_kernel<<<704, 256, 0, stream>>>(W1, W1f);
    l1m_kernel<<<2048, 256, 0, stream>>>(data, W1f, b1, beta1, thr1, s1bits);

    unsigned short* spk[2] = {spk0, spk1};
    for (int ck = 0; ck < T_STEPS / TCHUNK; ++ck) {
        const int t0 = ck * TCHUNK;
        expand_kernel<<<TCHUNK*BATCH, 256, 0, stream>>>(
            s1bits + (size_t)t0*BATCH*32, S1c);
        xw2_kernel<<<8*4*2*TCHUNK, 256, 0, stream>>>(S1c, Bsplit, X2c);
        for (int tt = 0; tt < TCHUNK; ++tt) {
            const int t = t0 + tt;
            vfull_kernel<<<256, 256, 0, stream>>>(
                spk[t & 1], Bsplit, X2c + (size_t)tt*BATCH*H2, b2,
                mem_r, ahp, spk[(t + 1) & 1], srbits + (size_t)t*BATCH*32,
                beta_r, thr_r, back_beta, alpha);
        }
    }
    w3out_kernel<<<256, 256, 0, stream>>>(srbits, W3, b3, out, beta2, thr2);
}

// Round 8
// 3763.761 us; speedup vs baseline: 1.8666x; 1.1516x over previous
//
#include <hip/hip_runtime.h>
#include <hip/hip_bf16.h>
#include <cstdint>

#define T_STEPS 100
#define BATCH 256
#define NIN 700
#define H1 2048
#define H2 2048
#define NOUT 20
#define VKS 8           // K-split factor for per-step V GEMM (grid 32nt x 8ks)
#define TCHUNK 10       // timesteps per hoisted-GEMM chunk (10 chunks)

typedef __attribute__((ext_vector_type(8))) short bf16x8;
typedef __attribute__((ext_vector_type(4))) float f32x4;
typedef unsigned long long ull;

__device__ __forceinline__ void async16(void* lds, const void* g) {
    __builtin_amdgcn_global_load_lds(
        (const __attribute__((address_space(1))) unsigned int*)g,
        (__attribute__((address_space(3))) unsigned int*)lds, 16, 0, 0);
}

__device__ __forceinline__ unsigned short f2bf(float x) {
    __hip_bfloat16 h = __float2bfloat16(x);
    return *(unsigned short*)&h;
}
__device__ __forceinline__ float bf2f(unsigned short u) {
    __hip_bfloat16 h = *(__hip_bfloat16*)&u;
    return __bfloat162float(h);
}

// unpack one byte of spike bits into 8 bf16 {0,1} packed as uint4 (round-0
// proven snippet).
__device__ __forceinline__ void byte_to_u4(unsigned int byte, unsigned int* u) {
    #pragma unroll
    for (int p = 0; p < 4; ++p) {
        int bit = p << 1;
        u[p] = (((byte >> bit) & 1u) ? 0x3F80u : 0u)
             | (((byte >> (bit + 1)) & 1u) ? 0x3F800000u : 0u);
    }
}

// ---------------- split W2|V into bf16 hi/mid/lo, layout [term][j][4096k] ----
// k<2048 = W2 row, k>=2048 = V row.
__global__ __launch_bounds__(256) void split_kernel(
    const float* __restrict__ W2, const float* __restrict__ V,
    unsigned short* __restrict__ Bsplit)
{
    const size_t D = (size_t)2048 * 4096;
    size_t i = (size_t)blockIdx.x * 256 + threadIdx.x;
    int j = (int)(i >> 12), k = (int)(i & 4095);
    float w = (k < 2048) ? W2[(size_t)j * 2048 + k] : V[(size_t)j * 2048 + (k - 2048)];
    unsigned short h = f2bf(w);
    float r1 = w - bf2f(h);
    unsigned short m = f2bf(r1);
    float r2 = r1 - bf2f(m);
    unsigned short l = f2bf(r2);
    Bsplit[i] = h;
    Bsplit[D + i] = m;
    Bsplit[2 * D + i] = l;
}

// ---------------- split W1 into granule-major bf16 planes ------------------
// W1f[term][g 0..87][j 0..2047][8] ; k = g*8+e, zero-padded k>=700.
__global__ __launch_bounds__(256) void w1split_kernel(
    const float* __restrict__ W1, unsigned short* __restrict__ W1f)
{
    const size_t P = (size_t)88 * 2048 * 8;   // elems per term
    int id = blockIdx.x * 256 + threadIdx.x;  // 0..180223
    int g = id >> 11, j = id & 2047;
    unsigned short h8[8], m8[8], l8[8];
    #pragma unroll
    for (int e = 0; e < 8; ++e) {
        int k = g * 8 + e;
        float v = (k < NIN) ? W1[(size_t)j * NIN + k] : 0.f;
        unsigned short h = f2bf(v); float r1 = v - bf2f(h);
        unsigned short m = f2bf(r1); float r2 = r1 - bf2f(m);
        h8[e] = h; m8[e] = m; l8[e] = f2bf(r2);
    }
    size_t base = (((size_t)g * 2048) + j) * 8;
    *(uint4*)(W1f + base)         = *(uint4*)h8;
    *(uint4*)(W1f + P + base)     = *(uint4*)m8;
    *(uint4*)(W1f + 2 * P + base) = *(uint4*)l8;
}

// ---------------- layer 1 via MFMA: x@W1.T (6-term bf16) + scan + bitpack ----
// grid 2048 = 8 jt (bid&7, XCD-locality) x 256 b. Block 256 thr / 4 waves.
// NOTE: bit-word w' of s1bits[(t*256+b)*32 + w'] covers j in [w'*64, w'*64+64).
__global__ __launch_bounds__(256) void l1m_kernel(
    const float* __restrict__ data, const unsigned short* __restrict__ W1f,
    const float* __restrict__ b1,
    const float* __restrict__ p_beta1, const float* __restrict__ p_thr1,
    ull* __restrict__ s1bits)
{
    __shared__ __align__(16) char smem[33280];  // union: Af 21.5KB | Cw 4x8.3KB
    unsigned short* Af = (unsigned short*)smem; // [3 term][4 g][112 t][8]
    const int tid = threadIdx.x, lane = tid & 63, w = tid >> 6;
    const int n16 = lane & 15, q = lane >> 4;
    const int jt = blockIdx.x & 7, b = blockIdx.x >> 3;
    const int j0w = jt * 256 + w * 64;
    const float* xb = data + (size_t)b * (NIN * T_STEPS);
    const size_t P = (size_t)88 * 2048 * 8;

    f32x4 acc[7][4] = {};
    for (int c = 0; c < 22; ++c) {
        const int kbase = c * 32;
        for (int it = tid; it < 448; it += 256) {
            int g = it / 112, t = it - g * 112;
            unsigned short h8[8], m8[8], l8[8];
            #pragma unroll
            for (int e = 0; e < 8; ++e) {
                int k = kbase + g * 8 + e;
                float v = (t < T_STEPS && k < NIN) ? xb[(size_t)k * T_STEPS + t] : 0.f;
                unsigned short h = f2bf(v); float r1 = v - bf2f(h);
                unsigned short m = f2bf(r1); float r2 = r1 - bf2f(m);
                h8[e] = h; m8[e] = m; l8[e] = f2bf(r2);
            }
            unsigned short* dst = Af + g * 896 + t * 8;
            *(uint4*)(dst)        = *(uint4*)h8;
            *(uint4*)(dst + 3584) = *(uint4*)m8;
            *(uint4*)(dst + 7168) = *(uint4*)l8;
        }
        __syncthreads();
        bf16x8 bh[4], bm[4], bl[4];
        const size_t gq = (size_t)(c * 4 + q);
        #pragma unroll
        for (int n = 0; n < 4; ++n) {
            size_t off = (gq * 2048 + (size_t)(j0w + n * 16 + n16)) * 8;
            bh[n] = *(const bf16x8*)(W1f + off);
            bm[n] = *(const bf16x8*)(W1f + P + off);
            bl[n] = *(const bf16x8*)(W1f + 2 * P + off);
        }
        #pragma unroll
        for (int m = 0; m < 7; ++m) {
            const unsigned short* ap = Af + q * 896 + (m * 16 + n16) * 8;
            bf16x8 ah = *(const bf16x8*)(ap);
            bf16x8 am = *(const bf16x8*)(ap + 3584);
            bf16x8 al = *(const bf16x8*)(ap + 7168);
            #pragma unroll
            for (int n = 0; n < 4; ++n) {
                acc[m][n] = __builtin_amdgcn_mfma_f32_16x16x32_bf16(ah, bh[n], acc[m][n], 0, 0, 0);
                acc[m][n] = __builtin_amdgcn_mfma_f32_16x16x32_bf16(ah, bm[n], acc[m][n], 0, 0, 0);
                acc[m][n] = __builtin_amdgcn_mfma_f32_16x16x32_bf16(am, bh[n], acc[m][n], 0, 0, 0);
                acc[m][n] = __builtin_amdgcn_mfma_f32_16x16x32_bf16(ah, bl[n], acc[m][n], 0, 0, 0);
                acc[m][n] = __builtin_amdgcn_mfma_f32_16x16x32_bf16(al, bh[n], acc[m][n], 0, 0, 0);
                acc[m][n] = __builtin_amdgcn_mfma_f32_16x16x32_bf16(am, bm[n], acc[m][n], 0, 0, 0);
            }
        }
        __syncthreads();
    }
    // epilogue: per-wave transpose (32 t at a time) + leaky scan + bitpack
    float* Cw = (float*)smem + w * (32 * 65);
    const float beta1 = *p_beta1, thr1 = *p_thr1;
    const float b1j = b1[j0w + lane];
    float mem = 0.f;
    for (int s = 0; s < 4; ++s) {
        #pragma unroll
        for (int mm = 0; mm < 2; ++mm) {
            int m = s * 2 + mm;
            if (m < 7) {
                #pragma unroll
                for (int n = 0; n < 4; ++n)
                    #pragma unroll
                    for (int r = 0; r < 4; ++r)
                        Cw[(mm * 16 + q * 4 + r) * 65 + n * 16 + n16] = acc[m][n][r];
            }
        }
        int tcnt = (s < 3) ? 32 : 4;
        for (int tt = 0; tt < tcnt; ++tt) {
            float v = Cw[tt * 65 + lane];
            mem = fmaf(beta1, mem, v) + b1j;
            bool pred = (mem - thr1) > 0.f;
            ull mask = __ballot(pred);
            if (pred) mem -= thr1;
            if (lane == 0) {
                int tg = s * 32 + tt;
                s1bits[((size_t)tg * BATCH + b) * 32 + jt * 4 + w] = mask;
            }
        }
    }
}

// ---------------- hoisted GEMM (per chunk): X2c = S1c @ W2.T ---------------
// 128-row tiles: grid 640 = 8 xcd x (4 ntl x 20 mt). LDS 40KB.
// A staged from BITS: per chunk c, row r needs exactly word bits0[row*32+c];
// in-register unpack -> XOR-swizzled ds_write (round-0 proven path). Kills
// the ~335 MB/chunk bf16-plane read amplification and the expand kernel.
__global__ __launch_bounds__(256, 2) void xw2_kernel(
    const ull* __restrict__ bits0,          // s1bits + t0*BATCH*32
    const unsigned short* __restrict__ Bsplit,
    float* __restrict__ X2c)
{
    __shared__ __align__(16) unsigned short Alds[128 * 64];    // 16 KB
    __shared__ __align__(16) unsigned short Blds[3 * 64 * 64]; // 24 KB
    const int bid = blockIdx.x;
    const int x = bid & 7;
    const int i = bid >> 3;           // 0..79
    const int ntl = i / 20;           // 0..3
    const int mt = i - ntl * 20;      // 0..19 (128-row tile)
    const int n0 = (x * 4 + ntl) << 6;
    const int tid = threadIdx.x, lane = tid & 63, w = tid >> 6;
    const int ar = tid >> 1, ah2 = tid & 1;   // A-unpack: row, half-word
    f32x4 acc[2][4] = {};
    for (int c = 0; c < 32; ++c) {
        const int kin = c << 6;
        {   // stage A 128x64 from bits: 4 granules/thread
            ull word = bits0[(size_t)(mt * 128 + ar) * 32 + c];
            unsigned int half = (unsigned int)(word >> (ah2 * 32));
            #pragma unroll
            for (int gi2 = 0; gi2 < 4; ++gi2) {
                int g = (ah2 << 2) + gi2;
                unsigned int u[4];
                byte_to_u4((half >> (gi2 * 8)) & 0xFFu, u);
                int slot = (ar << 3) + (g ^ (ar & 7));
                *(uint4*)(Alds + (slot << 3)) = *(uint4*)u;
            }
        }
        #pragma unroll
        for (int term = 0; term < 3; ++term) {
            const unsigned short* Bg = Bsplit + ((size_t)term << 23);
            #pragma unroll
            for (int ii = 0; ii < 2; ++ii) {
                int d = (w << 7) + (ii << 6) + lane;
                int row = d >> 3, g8 = d & 7;
                async16(Blds + (((term << 9) + (w << 7) + (ii << 6)) << 3),
                        Bg + (size_t)(n0 + row) * 4096 + kin + ((g8 ^ (row & 7)) << 3));
            }
        }
        __syncthreads();
        #pragma unroll
        for (int kk = 0; kk < 2; ++kk) {
            const int q = lane >> 4, k16 = (kk << 2) + q;
            bf16x8 af[2];
            #pragma unroll
            for (int ii = 0; ii < 2; ++ii) {
                int ra = (w << 5) + (ii << 4) + (lane & 15);
                af[ii] = *(const bf16x8*)(Alds + (((ra << 3) + (k16 ^ (ra & 7))) << 3));
            }
            #pragma unroll
            for (int term = 0; term < 3; ++term) {
                bf16x8 bfr[4];
                #pragma unroll
                for (int j = 0; j < 4; ++j) {
                    int rb = (j << 4) + (lane & 15);
                    bfr[j] = *(const bf16x8*)(Blds +
                              (((term << 9) + (rb << 3) + (k16 ^ (rb & 7))) << 3));
                }
                #pragma unroll
                for (int ii = 0; ii < 2; ++ii)
                    #pragma unroll
                    for (int j = 0; j < 4; ++j)
                        acc[ii][j] = __builtin_amdgcn_mfma_f32_16x16x32_bf16(
                            af[ii], bfr[j], acc[ii][j], 0, 0, 0);
            }
        }
        __syncthreads();
    }
    float* Xp = X2c + ((size_t)mt << 7) * 2048;
    #pragma unroll
    for (int ii = 0; ii < 2; ++ii) {
        int rg = (w << 5) + (ii << 4) + ((lane >> 4) << 2);
        #pragma unroll
        for (int j = 0; j < 4; ++j) {
            int cg = n0 + (j << 4) + (lane & 15);
            #pragma unroll
            for (int r = 0; r < 4; ++r)
                Xp[(size_t)(rg + r) * 2048 + cg] = acc[ii][j][r];
        }
    }
}

// ---------------- per-step V GEMM: Cpart[ks][256b][2048j] = spk_r @ V.T ----
// A from srbits (written by l2fin): per chunk, row b needs word
// srb_in[b*32 + ks*4 + c]; unpack verbatim from round-0's proven l2gemm.
__global__ __launch_bounds__(256, 2) void vgemm_kernel(
    const ull* __restrict__ srb_in,            // srbits plane for step t
    const unsigned short* __restrict__ Bsplit,
    float* __restrict__ Cpart)
{
    __shared__ __align__(16) unsigned short Alds[256 * 64];    // 32 KB
    __shared__ __align__(16) unsigned short Blds[3 * 64 * 64]; // 24 KB
    const int bid = blockIdx.x;
    const int nt = bid & 31, ks = bid >> 5;
    const int n0 = nt << 6;
    const int tid = threadIdx.x, lane = tid & 63, w = tid >> 6;
    f32x4 acc[4][4] = {};
    for (int c = 0; c < 4; ++c) {
        const int kin = (ks << 8) + (c << 6);
        {   // stage A 256x64 from bits: 8 granules/thread (row = tid)
            ull word = srb_in[((size_t)tid << 5) + (ks << 2) + c];
            #pragma unroll
            for (int g8 = 0; g8 < 8; ++g8) {
                unsigned int u[4];
                byte_to_u4((unsigned int)(word >> (g8 << 3)) & 0xFFu, u);
                int gdst = (tid << 3) + (g8 ^ (tid & 7));
                *(uint4*)(Alds + (gdst << 3)) = *(uint4*)u;
            }
        }
        #pragma unroll
        for (int term = 0; term < 3; ++term) {
            const unsigned short* Bg = Bsplit + ((size_t)term << 23);
            #pragma unroll
            for (int ii = 0; ii < 2; ++ii) {
                int d = (w << 7) + (ii << 6) + lane;
                int row = d >> 3, g8 = d & 7;
                // V region: column offset 2048 within the 4096-stride row
                async16(Blds + (((term << 9) + (w << 7) + (ii << 6)) << 3),
                        Bg + (size_t)(n0 + row) * 4096 + 2048 + kin + ((g8 ^ (row & 7)) << 3));
            }
        }
        __syncthreads();
        #pragma unroll
        for (int kk = 0; kk < 2; ++kk) {
            const int q = lane >> 4, k16 = (kk << 2) + q;
            bf16x8 af[4];
            #pragma unroll
            for (int ii = 0; ii < 4; ++ii) {
                int ra = (w << 6) + (ii << 4) + (lane & 15);
                af[ii] = *(const bf16x8*)(Alds + (((ra << 3) + (k16 ^ (ra & 7))) << 3));
            }
            #pragma unroll
            for (int term = 0; term < 3; ++term) {
                bf16x8 bfr[4];
                #pragma unroll
                for (int j = 0; j < 4; ++j) {
                    int rb = (j << 4) + (lane & 15);
                    bfr[j] = *(const bf16x8*)(Blds +
                              (((term << 9) + (rb << 3) + (k16 ^ (rb & 7))) << 3));
                }
                #pragma unroll
                for (int ii = 0; ii < 4; ++ii)
                    #pragma unroll
                    for (int j = 0; j < 4; ++j)
                        acc[ii][j] = __builtin_amdgcn_mfma_f32_16x16x32_bf16(
                            af[ii], bfr[j], acc[ii][j], 0, 0, 0);
            }
        }
        __syncthreads();
    }
    float* Cp = Cpart + ((size_t)ks << 19);
    #pragma unroll
    for (int ii = 0; ii < 4; ++ii) {
        int rg = (w << 6) + (ii << 4) + ((lane >> 4) << 2);
        #pragma unroll
        for (int j = 0; j < 4; ++j) {
            int cg = n0 + (j << 4) + (lane & 15);
            #pragma unroll
            for (int r = 0; r < 4; ++r)
                Cp[(size_t)(rg + r) * 2048 + cg] = acc[ii][j][r];
        }
    }
}

// ---------------- slim finish (per step): partials + X2[t] + b2, AHP -------
// neuron, spike bits only (consumed by next vgemm AND deferred w3out).
__global__ __launch_bounds__(256) void l2fin_kernel(
    const float* __restrict__ Cpart, const float* __restrict__ X2t,
    const float* __restrict__ b2,
    float* __restrict__ mem_r, float* __restrict__ ahp,
    ull* __restrict__ srbits_out,              // srbits plane for step t+1
    const float* __restrict__ p_beta_r, const float* __restrict__ p_thr_r,
    const float* __restrict__ p_back_beta, const float* __restrict__ p_alpha)
{
    const int b = blockIdx.x, t = threadIdx.x;
    const int lane = t & 63, wv = t >> 6;
    const float beta_r = *p_beta_r, thr_r = *p_thr_r;
    const float bb = *p_back_beta, al = *p_alpha;
    #pragma unroll
    for (int u = 0; u < 8; ++u) {
        int j = t + (u << 8);
        size_t cidx = (size_t)b * 2048 + j;
        float x = 0.f;
        #pragma unroll
        for (int p = 0; p < VKS; ++p) x += Cpart[((size_t)p << 19) + cidx];
        float cur = x + X2t[cidx] + b2[j];
        float m = fmaf(beta_r, mem_r[cidx], cur) - ahp[cidx];
        bool pred = (m - thr_r) > 0.f;
        ull mask = __ballot(pred);
        float s = pred ? 1.f : 0.f;
        if (pred) m -= thr_r;
        mem_r[cidx] = m;
        ahp[cidx] = fmaf(bb, ahp[cidx], al * s);
        if (lane == 0) srbits_out[((size_t)b << 5) + (u << 2) + wv] = mask;
    }
}

// ---------------- deferred layer 3: all 100 steps in one launch ------------
// grid 256 (b). Bits staged in LDS; W3 in registers (2 passes x 10 outputs);
// verified in round 3 (absmax 0).
__global__ __launch_bounds__(256) void w3out_kernel(
    const ull* __restrict__ srbits, const float* __restrict__ W3,
    const float* __restrict__ b3, float* __restrict__ out,
    const float* __restrict__ p_beta2, const float* __restrict__ p_thr2)
{
    __shared__ ull bitsLDS[T_STEPS * 32];   // 25.6 KB
    __shared__ float red[4][10];
    const int b = blockIdx.x, tid = threadIdx.x, lane = tid & 63, wv = tid >> 6;
    for (int i = tid; i < T_STEPS * 32; i += 256)
        bitsLDS[i] = srbits[((size_t)(i >> 5) * BATCH + b) * 32 + (i & 31)];
    __syncthreads();
    const float beta2 = *p_beta2, thr2 = *p_thr2;
    for (int pass = 0; pass < 2; ++pass) {
        float w8[10][8];
        #pragma unroll
        for (int o = 0; o < 10; ++o) {
            const float4* wp = (const float4*)(W3 + (size_t)(pass * 10 + o) * 2048 + tid * 8);
            float4 a = wp[0], c = wp[1];
            w8[o][0] = a.x; w8[o][1] = a.y; w8[o][2] = a.z; w8[o][3] = a.w;
            w8[o][4] = c.x; w8[o][5] = c.y; w8[o][6] = c.z; w8[o][7] = c.w;
        }
        float m2 = 0.f;
        for (int t = 0; t < T_STEPS; ++t) {
            ull word = bitsLDS[(t << 5) + (tid >> 3)];
            unsigned int byte = (unsigned int)(word >> ((tid & 7) * 8)) & 0xFFu;
            float po[10];
            #pragma unroll
            for (int o = 0; o < 10; ++o) {
                float v = 0.f;
                #pragma unroll
                for (int e = 0; e < 8; ++e)
                    v += ((byte >> e) & 1u) ? w8[o][e] : 0.f;
                #pragma unroll
                for (int msk = 32; msk > 0; msk >>= 1)
                    v += __shfl_xor(v, msk, 64);
                po[o] = v;
            }
            if (lane == 0) {
                #pragma unroll
                for (int o = 0; o < 10; ++o) red[wv][o] = po[o];
            }
            __syncthreads();
            if (tid < 10) {
                float cur = red[0][tid] + red[1][tid] + red[2][tid] + red[3][tid]
                          + b3[pass * 10 + tid];
                float m = fmaf(beta2, m2, cur);
                bool pred = (m - thr2) > 0.f;
                float s2 = pred ? 1.f : 0.f;
                if (pred) m -= thr2;
                m2 = m;
                out[((size_t)t * BATCH + b) * NOUT + pass * 10 + tid] = s2;
            }
            __syncthreads();
        }
    }
}

extern "C" void kernel_launch(void* const* d_in, const int* in_sizes, int n_in,
                              void* d_out, int out_size, void* d_ws, size_t ws_size,
                              hipStream_t stream)
{
    const float* data   = (const float*)d_in[0];
    const float* W1     = (const float*)d_in[1];
    const float* b1     = (const float*)d_in[2];
    const float* W2     = (const float*)d_in[3];
    const float* b2     = (const float*)d_in[4];
    const float* V      = (const float*)d_in[5];
    const float* W3     = (const float*)d_in[6];
    const float* b3     = (const float*)d_in[7];
    const float* beta1  = (const float*)d_in[8];
    const float* thr1   = (const float*)d_in[9];
    const float* beta_r = (const float*)d_in[10];
    const float* thr_r  = (const float*)d_in[11];
    const float* back_beta = (const float*)d_in[12];
    const float* alpha  = (const float*)d_in[13];
    const float* beta2  = (const float*)d_in[14];
    const float* thr2   = (const float*)d_in[15];
    float* out = (float*)d_out;
    (void)in_sizes; (void)n_in; (void)out_size; (void)ws_size;

    const size_t PLANE = (size_t)BATCH * 32;   // ull words per srbits plane

    char* p = (char*)d_ws;
    auto carve = [&](size_t bytes) {
        char* r = p; p += (bytes + 255) & ~(size_t)255; return r;
    };
    // total carved: ~114 MB
    ull* s1bits = (ull*)carve((size_t)T_STEPS*BATCH*32*8);                   // 6.55 MB
    ull* srbAll = (ull*)carve((size_t)(T_STEPS+1)*BATCH*32*8);               // 6.62 MB
    float* mem_r = (float*)carve((size_t)BATCH*H2*4);                        // 2.1 MB
    float* ahp   = (float*)carve((size_t)BATCH*H2*4);                        // 2.1 MB
    unsigned short* Bsplit = (unsigned short*)carve((size_t)3*2048*4096*2);  // 50.3 MB
    float* Cpart = (float*)carve((size_t)VKS*BATCH*H2*4);                    // 16.8 MB
    float* X2c = (float*)carve((size_t)TCHUNK*BATCH*H2*4);                   // 21 MB
    unsigned short* W1f = (unsigned short*)carve((size_t)3*88*2048*8*2);     // 8.65 MB

    hipMemsetAsync(srbAll, 0, PLANE*8, stream);      // step -1 spikes = 0
    hipMemsetAsync(mem_r, 0, (size_t)BATCH*H2*4, stream);
    hipMemsetAsync(ahp,  0, (size_t)BATCH*H2*4, stream);

    split_kernel<<<(2048*4096)/256, 256, 0, stream>>>(W2, V, Bsplit);
    w1split_kernel<<<704, 256, 0, stream>>>(W1, W1f);
    l1m_kernel<<<2048, 256, 0, stream>>>(data, W1f, b1, beta1, thr1, s1bits);

    for (int ck = 0; ck < T_STEPS / TCHUNK; ++ck) {
        const int t0 = ck * TCHUNK;
        xw2_kernel<<<640, 256, 0, stream>>>(s1bits + (size_t)t0*BATCH*32,
                                            Bsplit, X2c);
        for (int tt = 0; tt < TCHUNK; ++tt) {
            const int t = t0 + tt;
            vgemm_kernel<<<256, 256, 0, stream>>>(srbAll + (size_t)t*PLANE,
                                                  Bsplit, Cpart);
            l2fin_kernel<<<256, 256, 0, stream>>>(Cpart,
                                                  X2c + (size_t)tt*BATCH*H2, b2,
                                                  mem_r, ahp,
                                                  srbAll + (size_t)(t+1)*PLANE,
                                                  beta_r, thr_r, back_beta, alpha);
        }
    }
    w3out_kernel<<<256, 256, 0, stream>>>(srbAll + PLANE, W3, b3, out,
                                          beta2, thr2);
}

// Round 9
// 3343.139 us; speedup vs baseline: 2.1014x; 1.1258x over previous
//
#include <hip/hip_runtime.h>
#include <hip/hip_bf16.h>
#include <cstdint>

#define T_STEPS 100
#define BATCH 256
#define NIN 700
#define H1 2048
#define H2 2048
#define NOUT 20
#define VKS 8           // K-split factor for per-step V GEMM (grid 32nt x 8ks)
#define TCHUNK 10       // timesteps per hoisted-GEMM chunk (10 chunks)

typedef __attribute__((ext_vector_type(8))) short bf16x8;
typedef __attribute__((ext_vector_type(4))) float f32x4;
typedef unsigned long long ull;

__device__ __forceinline__ void async16(void* lds, const void* g) {
    __builtin_amdgcn_global_load_lds(
        (const __attribute__((address_space(1))) unsigned int*)g,
        (__attribute__((address_space(3))) unsigned int*)lds, 16, 0, 0);
}

__device__ __forceinline__ unsigned short f2bf(float x) {
    __hip_bfloat16 h = __float2bfloat16(x);
    return *(unsigned short*)&h;
}
__device__ __forceinline__ float bf2f(unsigned short u) {
    __hip_bfloat16 h = *(__hip_bfloat16*)&u;
    return __bfloat162float(h);
}

// unpack one byte of spike bits into 8 bf16 {0,1} packed as uint4 (round-0
// proven snippet).
__device__ __forceinline__ void byte_to_u4(unsigned int byte, unsigned int* u) {
    #pragma unroll
    for (int p = 0; p < 4; ++p) {
        int bit = p << 1;
        u[p] = (((byte >> bit) & 1u) ? 0x3F80u : 0u)
             | (((byte >> (bit + 1)) & 1u) ? 0x3F800000u : 0u);
    }
}

// ---------------- split W2|V into bf16 hi/mid/lo, layout [term][j][4096k] ----
// k<2048 = W2 row, k>=2048 = V row.
__global__ __launch_bounds__(256) void split_kernel(
    const float* __restrict__ W2, const float* __restrict__ V,
    unsigned short* __restrict__ Bsplit)
{
    const size_t D = (size_t)2048 * 4096;
    size_t i = (size_t)blockIdx.x * 256 + threadIdx.x;
    int j = (int)(i >> 12), k = (int)(i & 4095);
    float w = (k < 2048) ? W2[(size_t)j * 2048 + k] : V[(size_t)j * 2048 + (k - 2048)];
    unsigned short h = f2bf(w);
    float r1 = w - bf2f(h);
    unsigned short m = f2bf(r1);
    float r2 = r1 - bf2f(m);
    unsigned short l = f2bf(r2);
    Bsplit[i] = h;
    Bsplit[D + i] = m;
    Bsplit[2 * D + i] = l;
}

// ---------------- split W1 into granule-major bf16 planes ------------------
// W1f[term][g 0..87][j 0..2047][8] ; k = g*8+e, zero-padded k>=700.
__global__ __launch_bounds__(256) void w1split_kernel(
    const float* __restrict__ W1, unsigned short* __restrict__ W1f)
{
    const size_t P = (size_t)88 * 2048 * 8;   // elems per term
    int id = blockIdx.x * 256 + threadIdx.x;  // 0..180223
    int g = id >> 11, j = id & 2047;
    unsigned short h8[8], m8[8], l8[8];
    #pragma unroll
    for (int e = 0; e < 8; ++e) {
        int k = g * 8 + e;
        float v = (k < NIN) ? W1[(size_t)j * NIN + k] : 0.f;
        unsigned short h = f2bf(v); float r1 = v - bf2f(h);
        unsigned short m = f2bf(r1); float r2 = r1 - bf2f(m);
        h8[e] = h; m8[e] = m; l8[e] = f2bf(r2);
    }
    size_t base = (((size_t)g * 2048) + j) * 8;
    *(uint4*)(W1f + base)         = *(uint4*)h8;
    *(uint4*)(W1f + P + base)     = *(uint4*)m8;
    *(uint4*)(W1f + 2 * P + base) = *(uint4*)l8;
}

// ---------------- layer 1 via MFMA: x@W1.T (6-term bf16) + scan + bitpack ----
// grid 2048 = 8 jt (bid&7, XCD-locality) x 256 b. Block 256 thr / 4 waves.
// NOTE: bit-word w' of s1bits[(t*256+b)*32 + w'] covers j in [w'*64, w'*64+64).
__global__ __launch_bounds__(256) void l1m_kernel(
    const float* __restrict__ data, const unsigned short* __restrict__ W1f,
    const float* __restrict__ b1,
    const float* __restrict__ p_beta1, const float* __restrict__ p_thr1,
    ull* __restrict__ s1bits)
{
    __shared__ __align__(16) char smem[33280];  // union: Af 21.5KB | Cw 4x8.3KB
    unsigned short* Af = (unsigned short*)smem; // [3 term][4 g][112 t][8]
    const int tid = threadIdx.x, lane = tid & 63, w = tid >> 6;
    const int n16 = lane & 15, q = lane >> 4;
    const int jt = blockIdx.x & 7, b = blockIdx.x >> 3;
    const int j0w = jt * 256 + w * 64;
    const float* xb = data + (size_t)b * (NIN * T_STEPS);
    const size_t P = (size_t)88 * 2048 * 8;

    f32x4 acc[7][4] = {};
    for (int c = 0; c < 22; ++c) {
        const int kbase = c * 32;
        for (int it = tid; it < 448; it += 256) {
            int g = it / 112, t = it - g * 112;
            unsigned short h8[8], m8[8], l8[8];
            #pragma unroll
            for (int e = 0; e < 8; ++e) {
                int k = kbase + g * 8 + e;
                float v = (t < T_STEPS && k < NIN) ? xb[(size_t)k * T_STEPS + t] : 0.f;
                unsigned short h = f2bf(v); float r1 = v - bf2f(h);
                unsigned short m = f2bf(r1); float r2 = r1 - bf2f(m);
                h8[e] = h; m8[e] = m; l8[e] = f2bf(r2);
            }
            unsigned short* dst = Af + g * 896 + t * 8;
            *(uint4*)(dst)        = *(uint4*)h8;
            *(uint4*)(dst + 3584) = *(uint4*)m8;
            *(uint4*)(dst + 7168) = *(uint4*)l8;
        }
        __syncthreads();
        bf16x8 bh[4], bm[4], bl[4];
        const size_t gq = (size_t)(c * 4 + q);
        #pragma unroll
        for (int n = 0; n < 4; ++n) {
            size_t off = (gq * 2048 + (size_t)(j0w + n * 16 + n16)) * 8;
            bh[n] = *(const bf16x8*)(W1f + off);
            bm[n] = *(const bf16x8*)(W1f + P + off);
            bl[n] = *(const bf16x8*)(W1f + 2 * P + off);
        }
        #pragma unroll
        for (int m = 0; m < 7; ++m) {
            const unsigned short* ap = Af + q * 896 + (m * 16 + n16) * 8;
            bf16x8 ah = *(const bf16x8*)(ap);
            bf16x8 am = *(const bf16x8*)(ap + 3584);
            bf16x8 al = *(const bf16x8*)(ap + 7168);
            #pragma unroll
            for (int n = 0; n < 4; ++n) {
                acc[m][n] = __builtin_amdgcn_mfma_f32_16x16x32_bf16(ah, bh[n], acc[m][n], 0, 0, 0);
                acc[m][n] = __builtin_amdgcn_mfma_f32_16x16x32_bf16(ah, bm[n], acc[m][n], 0, 0, 0);
                acc[m][n] = __builtin_amdgcn_mfma_f32_16x16x32_bf16(am, bh[n], acc[m][n], 0, 0, 0);
                acc[m][n] = __builtin_amdgcn_mfma_f32_16x16x32_bf16(ah, bl[n], acc[m][n], 0, 0, 0);
                acc[m][n] = __builtin_amdgcn_mfma_f32_16x16x32_bf16(al, bh[n], acc[m][n], 0, 0, 0);
                acc[m][n] = __builtin_amdgcn_mfma_f32_16x16x32_bf16(am, bm[n], acc[m][n], 0, 0, 0);
            }
        }
        __syncthreads();
    }
    // epilogue: per-wave transpose (32 t at a time) + leaky scan + bitpack
    float* Cw = (float*)smem + w * (32 * 65);
    const float beta1 = *p_beta1, thr1 = *p_thr1;
    const float b1j = b1[j0w + lane];
    float mem = 0.f;
    for (int s = 0; s < 4; ++s) {
        #pragma unroll
        for (int mm = 0; mm < 2; ++mm) {
            int m = s * 2 + mm;
            if (m < 7) {
                #pragma unroll
                for (int n = 0; n < 4; ++n)
                    #pragma unroll
                    for (int r = 0; r < 4; ++r)
                        Cw[(mm * 16 + q * 4 + r) * 65 + n * 16 + n16] = acc[m][n][r];
            }
        }
        int tcnt = (s < 3) ? 32 : 4;
        for (int tt = 0; tt < tcnt; ++tt) {
            float v = Cw[tt * 65 + lane];
            mem = fmaf(beta1, mem, v) + b1j;
            bool pred = (mem - thr1) > 0.f;
            ull mask = __ballot(pred);
            if (pred) mem -= thr1;
            if (lane == 0) {
                int tg = s * 32 + tt;
                s1bits[((size_t)tg * BATCH + b) * 32 + jt * 4 + w] = mask;
            }
        }
    }
}

// ---------------- hoisted GEMM (per chunk): X2c = S1c @ W2.T ---------------
// 128-row tiles: grid 640 = 8 xcd x (4 ntl x 20 mt). LDS 40KB.
// A staged from BITS (round-8 proven).
__global__ __launch_bounds__(256, 2) void xw2_kernel(
    const ull* __restrict__ bits0,          // s1bits + t0*BATCH*32
    const unsigned short* __restrict__ Bsplit,
    float* __restrict__ X2c)
{
    __shared__ __align__(16) unsigned short Alds[128 * 64];    // 16 KB
    __shared__ __align__(16) unsigned short Blds[3 * 64 * 64]; // 24 KB
    const int bid = blockIdx.x;
    const int x = bid & 7;
    const int i = bid >> 3;           // 0..79
    const int ntl = i / 20;           // 0..3
    const int mt = i - ntl * 20;      // 0..19 (128-row tile)
    const int n0 = (x * 4 + ntl) << 6;
    const int tid = threadIdx.x, lane = tid & 63, w = tid >> 6;
    const int ar = tid >> 1, ah2 = tid & 1;   // A-unpack: row, half-word
    f32x4 acc[2][4] = {};
    for (int c = 0; c < 32; ++c) {
        const int kin = c << 6;
        {   // stage A 128x64 from bits: 4 granules/thread
            ull word = bits0[(size_t)(mt * 128 + ar) * 32 + c];
            unsigned int half = (unsigned int)(word >> (ah2 * 32));
            #pragma unroll
            for (int gi2 = 0; gi2 < 4; ++gi2) {
                int g = (ah2 << 2) + gi2;
                unsigned int u[4];
                byte_to_u4((half >> (gi2 * 8)) & 0xFFu, u);
                int slot = (ar << 3) + (g ^ (ar & 7));
                *(uint4*)(Alds + (slot << 3)) = *(uint4*)u;
            }
        }
        #pragma unroll
        for (int term = 0; term < 3; ++term) {
            const unsigned short* Bg = Bsplit + ((size_t)term << 23);
            #pragma unroll
            for (int ii = 0; ii < 2; ++ii) {
                int d = (w << 7) + (ii << 6) + lane;
                int row = d >> 3, g8 = d & 7;
                async16(Blds + (((term << 9) + (w << 7) + (ii << 6)) << 3),
                        Bg + (size_t)(n0 + row) * 4096 + kin + ((g8 ^ (row & 7)) << 3));
            }
        }
        __syncthreads();
        #pragma unroll
        for (int kk = 0; kk < 2; ++kk) {
            const int q = lane >> 4, k16 = (kk << 2) + q;
            bf16x8 af[2];
            #pragma unroll
            for (int ii = 0; ii < 2; ++ii) {
                int ra = (w << 5) + (ii << 4) + (lane & 15);
                af[ii] = *(const bf16x8*)(Alds + (((ra << 3) + (k16 ^ (ra & 7))) << 3));
            }
            #pragma unroll
            for (int term = 0; term < 3; ++term) {
                bf16x8 bfr[4];
                #pragma unroll
                for (int j = 0; j < 4; ++j) {
                    int rb = (j << 4) + (lane & 15);
                    bfr[j] = *(const bf16x8*)(Blds +
                              (((term << 9) + (rb << 3) + (k16 ^ (rb & 7))) << 3));
                }
                #pragma unroll
                for (int ii = 0; ii < 2; ++ii)
                    #pragma unroll
                    for (int j = 0; j < 4; ++j)
                        acc[ii][j] = __builtin_amdgcn_mfma_f32_16x16x32_bf16(
                            af[ii], bfr[j], acc[ii][j], 0, 0, 0);
            }
        }
        __syncthreads();
    }
    float* Xp = X2c + ((size_t)mt << 7) * 2048;
    #pragma unroll
    for (int ii = 0; ii < 2; ++ii) {
        int rg = (w << 5) + (ii << 4) + ((lane >> 4) << 2);
        #pragma unroll
        for (int j = 0; j < 4; ++j) {
            int cg = n0 + (j << 4) + (lane & 15);
            #pragma unroll
            for (int r = 0; r < 4; ++r)
                Xp[(size_t)(rg + r) * 2048 + cg] = acc[ii][j][r];
        }
    }
}

// ---------------- per-step V GEMM: Cpart[ks][256b][2048j] = spk_r @ V.T ----
// 2-phase pipelined (T3-min): A+B double-buffered (112KB LDS), all 4 A-words
// hoisted to registers (32 contiguous bytes), stage(c+1) issued BEFORE the
// MFMA of chunk c, ONE barrier per chunk (5 total vs 8). Math order identical.
__global__ __launch_bounds__(256) void vgemm_kernel(
    const ull* __restrict__ srb_in,            // srbits plane for step t
    const unsigned short* __restrict__ Bsplit,
    float* __restrict__ Cpart)
{
    __shared__ __align__(16) unsigned short Alds[2][256 * 64];    // 64 KB
    __shared__ __align__(16) unsigned short Blds[2][3 * 64 * 64]; // 48 KB
    const int bid = blockIdx.x;
    const int nt = bid & 31, ks = bid >> 5;
    const int n0 = nt << 6;
    const int tid = threadIdx.x, lane = tid & 63, w = tid >> 6;
    // all 4 A-words for this thread's row up front (32B contiguous)
    ull aw[4];
    {
        const ull* wp = srb_in + ((size_t)tid << 5) + (ks << 2);
        aw[0] = wp[0]; aw[1] = wp[1]; aw[2] = wp[2]; aw[3] = wp[3];
    }
    auto stageA = [&](int c, int buf) {
        ull word = aw[c];
        #pragma unroll
        for (int g8 = 0; g8 < 8; ++g8) {
            unsigned int u[4];
            byte_to_u4((unsigned int)(word >> (g8 << 3)) & 0xFFu, u);
            int gdst = (tid << 3) + (g8 ^ (tid & 7));
            *(uint4*)(Alds[buf] + (gdst << 3)) = *(uint4*)u;
        }
    };
    auto stageB = [&](int c, int buf) {
        const int kin = (ks << 8) + (c << 6);
        #pragma unroll
        for (int term = 0; term < 3; ++term) {
            const unsigned short* Bg = Bsplit + ((size_t)term << 23);
            #pragma unroll
            for (int ii = 0; ii < 2; ++ii) {
                int d = (w << 7) + (ii << 6) + lane;
                int row = d >> 3, g8 = d & 7;
                // V region: column offset 2048 within the 4096-stride row
                async16(Blds[buf] + (((term << 9) + (w << 7) + (ii << 6)) << 3),
                        Bg + (size_t)(n0 + row) * 4096 + 2048 + kin + ((g8 ^ (row & 7)) << 3));
            }
        }
    };
    f32x4 acc[4][4] = {};
    stageB(0, 0);
    stageA(0, 0);
    __syncthreads();
    for (int c = 0; c < 4; ++c) {
        const int buf = c & 1;
        if (c < 3) {            // issue next-chunk staging before this MFMA
            stageB(c + 1, buf ^ 1);
            stageA(c + 1, buf ^ 1);
        }
        #pragma unroll
        for (int kk = 0; kk < 2; ++kk) {
            const int q = lane >> 4, k16 = (kk << 2) + q;
            bf16x8 af[4];
            #pragma unroll
            for (int ii = 0; ii < 4; ++ii) {
                int ra = (w << 6) + (ii << 4) + (lane & 15);
                af[ii] = *(const bf16x8*)(Alds[buf] + (((ra << 3) + (k16 ^ (ra & 7))) << 3));
            }
            #pragma unroll
            for (int term = 0; term < 3; ++term) {
                bf16x8 bfr[4];
                #pragma unroll
                for (int j = 0; j < 4; ++j) {
                    int rb = (j << 4) + (lane & 15);
                    bfr[j] = *(const bf16x8*)(Blds[buf] +
                              (((term << 9) + (rb << 3) + (k16 ^ (rb & 7))) << 3));
                }
                #pragma unroll
                for (int ii = 0; ii < 4; ++ii)
                    #pragma unroll
                    for (int j = 0; j < 4; ++j)
                        acc[ii][j] = __builtin_amdgcn_mfma_f32_16x16x32_bf16(
                            af[ii], bfr[j], acc[ii][j], 0, 0, 0);
            }
        }
        __syncthreads();        // drains next-chunk loads + protects buffers
    }
    float* Cp = Cpart + ((size_t)ks << 19);
    #pragma unroll
    for (int ii = 0; ii < 4; ++ii) {
        int rg = (w << 6) + (ii << 4) + ((lane >> 4) << 2);
        #pragma unroll
        for (int j = 0; j < 4; ++j) {
            int cg = n0 + (j << 4) + (lane & 15);
            #pragma unroll
            for (int r = 0; r < 4; ++r)
                Cp[(size_t)(rg + r) * 2048 + cg] = acc[ii][j][r];
        }
    }
}

// ---------------- slim finish (per step): partials + X2[t] + b2, AHP -------
// 1024 threads / 16 waves per block for L3-latency hiding; 2 neurons/thread.
// Per-neuron math order bit-identical to round 8; word (u<<4)+wv == j>>6.
__global__ __launch_bounds__(1024) void l2fin_kernel(
    const float* __restrict__ Cpart, const float* __restrict__ X2t,
    const float* __restrict__ b2,
    float* __restrict__ mem_r, float* __restrict__ ahp,
    ull* __restrict__ srbits_out,              // srbits plane for step t+1
    const float* __restrict__ p_beta_r, const float* __restrict__ p_thr_r,
    const float* __restrict__ p_back_beta, const float* __restrict__ p_alpha)
{
    const int b = blockIdx.x, tid = threadIdx.x;
    const int lane = tid & 63, wv = tid >> 6;   // wv 0..15
    const float beta_r = *p_beta_r, thr_r = *p_thr_r;
    const float bb = *p_back_beta, al = *p_alpha;
    #pragma unroll
    for (int u = 0; u < 2; ++u) {
        int j = tid + (u << 10);
        size_t cidx = ((size_t)b << 11) + j;
        float x = 0.f;
        #pragma unroll
        for (int p = 0; p < VKS; ++p) x += Cpart[((size_t)p << 19) + cidx];
        float cur = x + X2t[cidx] + b2[j];
        float m = fmaf(beta_r, mem_r[cidx], cur) - ahp[cidx];
        bool pred = (m - thr_r) > 0.f;
        ull mask = __ballot(pred);
        float s = pred ? 1.f : 0.f;
        if (pred) m -= thr_r;
        mem_r[cidx] = m;
        ahp[cidx] = fmaf(bb, ahp[cidx], al * s);
        if (lane == 0) srbits_out[((size_t)b << 5) + (u << 4) + wv] = mask;
    }
}

// ---------------- deferred layer 3: all 100 steps in one launch ------------
// grid 256 (b). Bits staged in LDS; W3 in registers (2 passes x 10 outputs);
// verified in round 3 (absmax 0).
__global__ __launch_bounds__(256) void w3out_kernel(
    const ull* __restrict__ srbits, const float* __restrict__ W3,
    const float* __restrict__ b3, float* __restrict__ out,
    const float* __restrict__ p_beta2, const float* __restrict__ p_thr2)
{
    __shared__ ull bitsLDS[T_STEPS * 32];   // 25.6 KB
    __shared__ float red[4][10];
    const int b = blockIdx.x, tid = threadIdx.x, lane = tid & 63, wv = tid >> 6;
    for (int i = tid; i < T_STEPS * 32; i += 256)
        bitsLDS[i] = srbits[((size_t)(i >> 5) * BATCH + b) * 32 + (i & 31)];
    __syncthreads();
    const float beta2 = *p_beta2, thr2 = *p_thr2;
    for (int pass = 0; pass < 2; ++pass) {
        float w8[10][8];
        #pragma unroll
        for (int o = 0; o < 10; ++o) {
            const float4* wp = (const float4*)(W3 + (size_t)(pass * 10 + o) * 2048 + tid * 8);
            float4 a = wp[0], c = wp[1];
            w8[o][0] = a.x; w8[o][1] = a.y; w8[o][2] = a.z; w8[o][3] = a.w;
            w8[o][4] = c.x; w8[o][5] = c.y; w8[o][6] = c.z; w8[o][7] = c.w;
        }
        float m2 = 0.f;
        for (int t = 0; t < T_STEPS; ++t) {
            ull word = bitsLDS[(t << 5) + (tid >> 3)];
            unsigned int byte = (unsigned int)(word >> ((tid & 7) * 8)) & 0xFFu;
            float po[10];
            #pragma unroll
            for (int o = 0; o < 10; ++o) {
                float v = 0.f;
                #pragma unroll
                for (int e = 0; e < 8; ++e)
                    v += ((byte >> e) & 1u) ? w8[o][e] : 0.f;
                #pragma unroll
                for (int msk = 32; msk > 0; msk >>= 1)
                    v += __shfl_xor(v, msk, 64);
                po[o] = v;
            }
            if (lane == 0) {
                #pragma unroll
                for (int o = 0; o < 10; ++o) red[wv][o] = po[o];
            }
            __syncthreads();
            if (tid < 10) {
                float cur = red[0][tid] + red[1][tid] + red[2][tid] + red[3][tid]
                          + b3[pass * 10 + tid];
                float m = fmaf(beta2, m2, cur);
                bool pred = (m - thr2) > 0.f;
                float s2 = pred ? 1.f : 0.f;
                if (pred) m -= thr2;
                m2 = m;
                out[((size_t)t * BATCH + b) * NOUT + pass * 10 + tid] = s2;
            }
            __syncthreads();
        }
    }
}

extern "C" void kernel_launch(void* const* d_in, const int* in_sizes, int n_in,
                              void* d_out, int out_size, void* d_ws, size_t ws_size,
                              hipStream_t stream)
{
    const float* data   = (const float*)d_in[0];
    const float* W1     = (const float*)d_in[1];
    const float* b1     = (const float*)d_in[2];
    const float* W2     = (const float*)d_in[3];
    const float* b2     = (const float*)d_in[4];
    const float* V      = (const float*)d_in[5];
    const float* W3     = (const float*)d_in[6];
    const float* b3     = (const float*)d_in[7];
    const float* beta1  = (const float*)d_in[8];
    const float* thr1   = (const float*)d_in[9];
    const float* beta_r = (const float*)d_in[10];
    const float* thr_r  = (const float*)d_in[11];
    const float* back_beta = (const float*)d_in[12];
    const float* alpha  = (const float*)d_in[13];
    const float* beta2  = (const float*)d_in[14];
    const float* thr2   = (const float*)d_in[15];
    float* out = (float*)d_out;
    (void)in_sizes; (void)n_in; (void)out_size; (void)ws_size;

    const size_t PLANE = (size_t)BATCH * 32;   // ull words per srbits plane

    char* p = (char*)d_ws;
    auto carve = [&](size_t bytes) {
        char* r = p; p += (bytes + 255) & ~(size_t)255; return r;
    };
    // total carved: ~114 MB
    ull* s1bits = (ull*)carve((size_t)T_STEPS*BATCH*32*8);                   // 6.55 MB
    ull* srbAll = (ull*)carve((size_t)(T_STEPS+1)*BATCH*32*8);               // 6.62 MB
    float* mem_r = (float*)carve((size_t)BATCH*H2*4);                        // 2.1 MB
    float* ahp   = (float*)carve((size_t)BATCH*H2*4);                        // 2.1 MB
    unsigned short* Bsplit = (unsigned short*)carve((size_t)3*2048*4096*2);  // 50.3 MB
    float* Cpart = (float*)carve((size_t)VKS*BATCH*H2*4);                    // 16.8 MB
    float* X2c = (float*)carve((size_t)TCHUNK*BATCH*H2*4);                   // 21 MB
    unsigned short* W1f = (unsigned short*)carve((size_t)3*88*2048*8*2);     // 8.65 MB

    hipMemsetAsync(srbAll, 0, PLANE*8, stream);      // step -1 spikes = 0
    hipMemsetAsync(mem_r, 0, (size_t)BATCH*H2*4, stream);
    hipMemsetAsync(ahp,  0, (size_t)BATCH*H2*4, stream);

    split_kernel<<<(2048*4096)/256, 256, 0, stream>>>(W2, V, Bsplit);
    w1split_kernel<<<704, 256, 0, stream>>>(W1, W1f);
    l1m_kernel<<<2048, 256, 0, stream>>>(data, W1f, b1, beta1, thr1, s1bits);

    for (int ck = 0; ck < T_STEPS / TCHUNK; ++ck) {
        const int t0 = ck * TCHUNK;
        xw2_kernel<<<640, 256, 0, stream>>>(s1bits + (size_t)t0*BATCH*32,
                                            Bsplit, X2c);
        for (int tt = 0; tt < TCHUNK; ++tt) {
            const int t = t0 + tt;
            vgemm_kernel<<<256, 256, 0, stream>>>(srbAll + (size_t)t*PLANE,
                                                  Bsplit, Cpart);
            l2fin_kernel<<<256, 1024, 0, stream>>>(Cpart,
                                                   X2c + (size_t)tt*BATCH*H2, b2,
                                                   mem_r, ahp,
                                                   srbAll + (size_t)(t+1)*PLANE,
                                                   beta_r, thr_r, back_beta, alpha);
        }
    }
    w3out_kernel<<<256, 256, 0, stream>>>(srbAll + PLANE, W3, b3, out,
                                          beta2, thr2);
}